// Round 7
// baseline (890.284 us; speedup 1.0000x reference)
//
#include <hip/hip_runtime.h>
#include <cmath>

// ---------------------------------------------------------------------------
// VQ-VAE forward, fp32. B=256, C=3, HW=64, D=256, K=8192, LAT=128
// R6: (a) LDA = TM+4 in gemmconv: As staging writes go 4-way -> 2-way bank
// conflict (free). (b) t3/t31 convT replaced by merged-parity kernel
// convt_merged: stage the 4 shifted input-pixel sets once each, run their
// 1-4 taps into 4 parity accumulators, single epilogue + one BN-stat pass
// (was 4 parity sub-GEMMs with K=32..128 each, setup/epilogue paid 4x).
// ---------------------------------------------------------------------------

#define EPS_BN 1e-5f

__device__ __forceinline__ float lrelu(float v) { return v >= 0.f ? v : 0.01f * v; }

// ======================= weight transposes (once per launch) ===============
// conv weights (COUT,CIN,3,3) -> wT[(t*CIN+ci)*COUT+co], t=ky*3+kx
__global__ __launch_bounds__(256) void tr_convw(const float* __restrict__ w,
                                                float* __restrict__ wT,
                                                int CIN, int COUT, int total) {
  int i = blockIdx.x * 256 + threadIdx.x;
  if (i >= total) return;
  int co = i % COUT;
  int tmp = i / COUT;
  int ci = tmp % CIN;
  int t = tmp / CIN;
  wT[i] = w[((size_t)co * CIN + ci) * 9 + t];
}

// convT weights (CIN,COUT,3,3) -> parity-concat wT, sizes {1,2,2,4}*CIN*COUT
__global__ __launch_bounds__(256) void tr_convtw(const float* __restrict__ w,
                                                 float* __restrict__ wT,
                                                 int CIN, int COUT, int total) {
  int i = blockIdx.x * 256 + threadIdx.x;
  if (i >= total) return;
  int u = i / (CIN * COUT);
  int rem = i % (CIN * COUT);
  int ci = rem / COUT, co = rem % COUT;
  int ky, kx;
  if (u == 0) { ky = 1; kx = 1; }
  else if (u <= 2) { ky = 1; kx = (u == 1) ? 0 : 2; }
  else if (u <= 4) { ky = (u == 3) ? 0 : 2; kx = 1; }
  else { int t = u - 5; ky = (t >> 1) ? 2 : 0; kx = (t & 1) ? 2 : 0; }
  wT[i] = w[((size_t)ci * COUT + co) * 9 + ky * 3 + kx];
}

// convT weights (CIN,COUT,3,3) -> wT[(t*CIN+ci)*COUT+co], t = ky*3+kx
// (tap-major layout for the merged-parity kernel)
__global__ __launch_bounds__(256) void tr_convtw_m(const float* __restrict__ w,
                                                   float* __restrict__ wT,
                                                   int CIN, int COUT, int total) {
  int i = blockIdx.x * 256 + threadIdx.x;
  if (i >= total) return;
  int co = i % COUT;
  int tmp = i / COUT;
  int ci = tmp % CIN;
  int t = tmp / CIN;
  wT[i] = w[((size_t)ci * COUT + co) * 9 + t];
}

// a4 NHWC [256,4,4,256] -> NCHW [256,256,4,4]
__global__ __launch_bounds__(256) void tr_a4(const float* __restrict__ in,
                                             float* __restrict__ out) {
  int i = blockIdx.x * 256 + threadIdx.x;  // 1048576
  int n = i >> 12, k = i & 4095;
  out[i] = in[(size_t)(n << 12) + ((k & 15) << 8) + (k >> 4)];
}

// wfc [4096,256] + bfc: permute ROWS from (c,y,x) to (y,x,c)
__global__ __launch_bounds__(256) void tr_fcdec(const float* __restrict__ in,
                                                const float* __restrict__ bin,
                                                float* __restrict__ out,
                                                float* __restrict__ bout) {
  int i = blockIdx.x * 256 + threadIdx.x;  // 4096*256
  int k = i >> 8, d = i & 255;
  int kp = (k & 15) * 256 + (k >> 4);
  out[(size_t)kp * 256 + d] = in[i];
  if (d == 0) bout[kp] = bin[k];
}

// ======================= implicit-GEMM conv / convT ========================
template <int TM, int TN, int MODE, int IH, int CIN, int COUT, bool HASN>
__global__ __launch_bounds__(256) void gemmconv(
    const float* __restrict__ X, const float* __restrict__ WT,
    const float* __restrict__ bias, const float* __restrict__ st, float invN,
    float* __restrict__ Y, float* __restrict__ stOut) {
  constexpr int OH = (MODE == 0) ? IH / 2 : 2 * IH;
  constexpr int MR = TM / 16, NR = TN / 16;
  constexpr int LDA = TM + 4;  // R6: +4 -> staging writes 2-way (free)
  constexpr int LDB = TN + 8;
  __shared__ float As[16][LDA];
  __shared__ float Bs[16][LDB];
  __shared__ float nrm0[HASN ? CIN : 4], nrm1[HASN ? CIN : 4];
  __shared__ float redS[16][LDB], redQ[16][LDB];
  const int tid = threadIdx.x;
  if (HASN) {
    for (int c = tid; c < CIN; c += 256) {
      float m = st[c] * invN;
      float var = st[256 + c] * invN - m * m;
      float s = rsqrtf(var + EPS_BN);
      nrm0[c] = s;
      nrm1[c] = m * s;
    }
    __syncthreads();
  }
  int py = 0, px = 0, nx = 1, K = 9 * CIN;
  int dy0 = 0, dy1 = 0, dx0 = 0, dx1 = 0;
  const float* W = WT;
  if (MODE == 1) {
    const int pz = blockIdx.z;
    py = pz >> 1;
    px = pz & 1;
    nx = px ? 2 : 1;
    const int ny = py ? 2 : 1;
    if (py) { dy0 = 1; dy1 = 0; }
    if (px) { dx0 = 1; dx1 = 0; }
    K = ny * nx * CIN;
    const int pre[4] = {0, 1, 3, 5};
    W = WT + (size_t)pre[pz] * CIN * COUT;
  }
  const int gyTM = blockIdx.y * TM;
  const int gxTN = blockIdx.x * TN;

  constexpr int NCH = (TM * 4 + 255) / 256;
  int chRow[NCH], chQ4[NCH], chIY[NCH], chIX[NCH];
  size_t chNB[NCH];
  bool chV[NCH];
#pragma unroll
  for (int c = 0; c < NCH; ++c) {
    const int i = tid + c * 256;
    chV[c] = i < TM * 4;
    if (chV[c]) {
      const int row = i >> 2;
      chRow[c] = row;
      chQ4[c] = (i & 3) * 4;
      const int m = gyTM + row;
      if (MODE == 0) {
        const int ni = m / (OH * OH), r = m % (OH * OH);
        chNB[c] = (size_t)ni * IH * IH;
        chIY[c] = 2 * (r / OH) - 1;
        chIX[c] = 2 * (r % OH) - 1;
      } else {
        const int ni = m / (IH * IH), r = m % (IH * IH);
        chNB[c] = (size_t)ni * IH * IH;
        chIY[c] = r / IH;
        chIX[c] = r % IH;
      }
    }
  }
  const int m0 = (tid >> 4) * MR, n0 = (tid & 15) * NR;
  float acc[MR][NR];
#pragma unroll
  for (int i = 0; i < MR; ++i)
#pragma unroll
    for (int j = 0; j < NR; ++j) acc[i][j] = 0.f;

  for (int k0 = 0; k0 < K; k0 += 16) {
    const int t = k0 / CIN, ci0 = k0 - t * CIN;
    int ky, kx;
    if (MODE == 0) {
      ky = t / 3;
      kx = t - ky * 3;
    } else {
      const int kyi = t / nx, kxi = t - kyi * nx;
      ky = kyi ? dy1 : dy0;
      kx = kxi ? dx1 : dx0;
    }
#pragma unroll
    for (int c = 0; c < NCH; ++c) {
      if (chV[c]) {
        const int iy = chIY[c] + ky, ix = chIX[c] + kx;
        const bool ok =
            ((unsigned)iy < (unsigned)IH) && ((unsigned)ix < (unsigned)IH);
        float4 v = make_float4(0.f, 0.f, 0.f, 0.f);
        if (ok) {
          v = *(const float4*)&X[(chNB[c] + iy * IH + ix) * CIN + ci0 + chQ4[c]];
          if (HASN) {
            const int cc = ci0 + chQ4[c];
            v.x = fmaf(v.x, nrm0[cc + 0], -nrm1[cc + 0]);
            v.y = fmaf(v.y, nrm0[cc + 1], -nrm1[cc + 1]);
            v.z = fmaf(v.z, nrm0[cc + 2], -nrm1[cc + 2]);
            v.w = fmaf(v.w, nrm0[cc + 3], -nrm1[cc + 3]);
          }
        }
        const int kq = chQ4[c], rw = chRow[c];
        As[kq + 0][rw] = v.x;
        As[kq + 1][rw] = v.y;
        As[kq + 2][rw] = v.z;
        As[kq + 3][rw] = v.w;
      }
    }
#pragma unroll
    for (int c = 0; c < (TN * 4 + 255) / 256; ++c) {
      const int i = tid + c * 256;
      if (i < TN * 4) {
        const int kk = i / (TN / 4);
        const int nc = (i % (TN / 4)) * 4;
        *(float4*)&Bs[kk][nc] =
            *(const float4*)&W[(size_t)(k0 + kk) * COUT + gxTN + nc];
      }
    }
    __syncthreads();
#pragma unroll
    for (int kk = 0; kk < 16; ++kk) {
      float a[MR], b[NR];
      if constexpr (MR == 2) {
        const float2 av = *(const float2*)&As[kk][m0];
        a[0] = av.x; a[1] = av.y;
      } else if constexpr (MR == 4) {
        const float4 av = *(const float4*)&As[kk][m0];
        a[0] = av.x; a[1] = av.y; a[2] = av.z; a[3] = av.w;
      } else {
        const float4 av = *(const float4*)&As[kk][m0];
        const float4 aw = *(const float4*)&As[kk][m0 + 4];
        a[0] = av.x; a[1] = av.y; a[2] = av.z; a[3] = av.w;
        a[4] = aw.x; a[5] = aw.y; a[6] = aw.z; a[7] = aw.w;
      }
      if constexpr (NR == 2) {
        const float2 bv = *(const float2*)&Bs[kk][n0];
        b[0] = bv.x; b[1] = bv.y;
      } else {
        const float4 bv = *(const float4*)&Bs[kk][n0];
        b[0] = bv.x; b[1] = bv.y; b[2] = bv.z; b[3] = bv.w;
      }
#pragma unroll
      for (int i = 0; i < MR; ++i)
#pragma unroll
        for (int j = 0; j < NR; ++j) acc[i][j] = fmaf(a[i], b[j], acc[i][j]);
    }
    __syncthreads();
  }

  float bv[NR], colS[NR], colQ[NR];
#pragma unroll
  for (int j = 0; j < NR; ++j) {
    bv[j] = bias[gxTN + n0 + j];
    colS[j] = 0.f;
    colQ[j] = 0.f;
  }
#pragma unroll
  for (int i = 0; i < MR; ++i) {
    const int m = gyTM + m0 + i;
    float o[NR];
#pragma unroll
    for (int j = 0; j < NR; ++j) {
      o[j] = lrelu(acc[i][j] + bv[j]);
      colS[j] += o[j];
      colQ[j] += o[j] * o[j];
    }
    size_t addr;
    if (MODE == 0) {
      const int ni = m / (OH * OH), r = m % (OH * OH);
      addr = (((size_t)ni * OH + r / OH) * OH + r % OH) * COUT + gxTN + n0;
    } else {
      const int ni = m / (IH * IH), r = m % (IH * IH);
      const int oy = 2 * (r / IH) + py, ox = 2 * (r % IH) + px;
      addr = (((size_t)ni * OH + oy) * OH + ox) * COUT + gxTN + n0;
    }
    if constexpr (NR == 4)
      *(float4*)&Y[addr] = make_float4(o[0], o[1], o[2], o[3]);
    else
      *(float2*)&Y[addr] = make_float2(o[0], o[1]);
  }
  const int rgrp = tid >> 4;
#pragma unroll
  for (int j = 0; j < NR; ++j) {
    redS[rgrp][n0 + j] = colS[j];
    redQ[rgrp][n0 + j] = colQ[j];
  }
  __syncthreads();
  if (tid < TN) {
    float S = 0.f, Q = 0.f;
#pragma unroll
    for (int r = 0; r < 16; ++r) {
      S += redS[r][tid];
      Q += redQ[r][tid];
    }
    atomicAdd(&stOut[gxTN + tid], S);
    atomicAdd(&stOut[256 + gxTN + tid], Q);
  }
}

// ======================= merged-parity convT (COUT=32, CIN<=64) ============
// TM=64 rows = input pixels; all 4 output parities accumulated in one pass.
// Per shift s=(dy,dx), the shifted input pixel set is staged ONCE, then its
// taps (weight (ky,kx) with dy=(ky==0), dx=(kx==0)) run against per-tap B
// tiles into acc[parity], parity=(ky==1?0:1, kx==1?0:1). Output quad of row
// (iy,ix) = (2iy+a, 2ix+b). Single epilogue + BN-stat pass.
template <int IH, int CIN, bool HASN>
__global__ __launch_bounds__(256) void convt_merged(
    const float* __restrict__ X, const float* __restrict__ WT,
    const float* __restrict__ bias, const float* __restrict__ st, float invN,
    float* __restrict__ Y, float* __restrict__ stOut) {
  constexpr int TM = 64, TN = 32, OH = 2 * IH;
  constexpr int LDA = TM + 4, LDB = TN + 8;
  constexpr int ACH = (CIN * TM) / 1024;  // float4 staging chunks / thread
  constexpr int BCH = CIN / 32;
  __shared__ float As[CIN][LDA];
  __shared__ float Bs[CIN][LDB];
  __shared__ float nrm0[HASN ? CIN : 4], nrm1[HASN ? CIN : 4];
  __shared__ float redS[16][LDB], redQ[16][LDB];
  const int tid = threadIdx.x;
  if (HASN) {
    for (int c = tid; c < CIN; c += 256) {
      float m = st[c] * invN;
      float var = st[256 + c] * invN - m * m;
      float s = rsqrtf(var + EPS_BN);
      nrm0[c] = s;
      nrm1[c] = m * s;
    }
  }
  const int gyTM = blockIdx.y * TM;
  // staging chunk coords: m = i&(TM-1) -> consecutive lanes, consecutive
  // pixels -> LDS writes conflict-free (2-way), L1 covers global strides.
  int cm[ACH], cn[ACH], ciy[ACH], cix[ACH], ckq[ACH];
#pragma unroll
  for (int c = 0; c < ACH; ++c) {
    const int i = tid + c * 256;
    const int m = i & (TM - 1);
    cm[c] = m;
    ckq[c] = (i / TM) * 4;
    const int gm = gyTM + m;
    cn[c] = gm / (IH * IH);
    const int r = gm % (IH * IH);
    ciy[c] = r / IH;
    cix[c] = r % IH;
  }
  const int m0 = (tid >> 4) * 4, n0 = (tid & 15) * 2;
  float acc[4][4][2];
#pragma unroll
  for (int p = 0; p < 4; ++p)
#pragma unroll
    for (int i = 0; i < 4; ++i) { acc[p][i][0] = 0.f; acc[p][i][1] = 0.f; }

  constexpr int NT[4] = {4, 2, 2, 1};
  constexpr int TT[4][4] = {{4, 5, 7, 8}, {3, 6, 0, 0}, {1, 2, 0, 0}, {0, 0, 0, 0}};
#pragma unroll
  for (int s = 0; s < 4; ++s) {
    const int dy = s >> 1, dx = s & 1;
    __syncthreads();  // prior compute done; also publishes nrm at s=0
#pragma unroll
    for (int c = 0; c < ACH; ++c) {
      const int iy = ciy[c] + dy, ix = cix[c] + dx;
      float4 v = make_float4(0.f, 0.f, 0.f, 0.f);
      if (iy < IH && ix < IH) {
        v = *(const float4*)&X[(((size_t)cn[c] * IH + iy) * IH + ix) * CIN +
                               ckq[c]];
        if (HASN) {
          const int cc = ckq[c];
          v.x = fmaf(v.x, nrm0[cc + 0], -nrm1[cc + 0]);
          v.y = fmaf(v.y, nrm0[cc + 1], -nrm1[cc + 1]);
          v.z = fmaf(v.z, nrm0[cc + 2], -nrm1[cc + 2]);
          v.w = fmaf(v.w, nrm0[cc + 3], -nrm1[cc + 3]);
        }
      }
      const int kq = ckq[c], m = cm[c];
      As[kq + 0][m] = v.x;
      As[kq + 1][m] = v.y;
      As[kq + 2][m] = v.z;
      As[kq + 3][m] = v.w;
    }
#pragma unroll
    for (int j = 0; j < NT[s]; ++j) {
      const int t = TT[s][j];
      const int ky = t / 3, kx = t % 3;
      const int par = ((ky == 1) ? 0 : 2) + ((kx == 1) ? 0 : 1);
      if (j > 0) __syncthreads();  // protect Bs from prior compute readers
#pragma unroll
      for (int c = 0; c < BCH; ++c) {
        const int i = tid + c * 256;
        const int kk = i >> 3, nc = (i & 7) * 4;
        *(float4*)&Bs[kk][nc] =
            *(const float4*)&WT[((size_t)t * CIN + kk) * 32 + nc];
      }
      __syncthreads();  // staging (As on j==0, Bs always) visible
#pragma unroll
      for (int kk = 0; kk < CIN; ++kk) {
        const float4 a = *(const float4*)&As[kk][m0];
        const float2 b = *(const float2*)&Bs[kk][n0];
        acc[par][0][0] = fmaf(a.x, b.x, acc[par][0][0]);
        acc[par][0][1] = fmaf(a.x, b.y, acc[par][0][1]);
        acc[par][1][0] = fmaf(a.y, b.x, acc[par][1][0]);
        acc[par][1][1] = fmaf(a.y, b.y, acc[par][1][1]);
        acc[par][2][0] = fmaf(a.z, b.x, acc[par][2][0]);
        acc[par][2][1] = fmaf(a.z, b.y, acc[par][2][1]);
        acc[par][3][0] = fmaf(a.w, b.x, acc[par][3][0]);
        acc[par][3][1] = fmaf(a.w, b.y, acc[par][3][1]);
      }
    }
  }

  const float bv0 = bias[n0], bv1 = bias[n0 + 1];
  float colS[2] = {0.f, 0.f}, colQ[2] = {0.f, 0.f};
#pragma unroll
  for (int i = 0; i < 4; ++i) {
    const int gm = gyTM + m0 + i;
    const int n = gm / (IH * IH);
    const int r = gm % (IH * IH);
    const int iy = r / IH, ix = r % IH;
#pragma unroll
    for (int p = 0; p < 4; ++p) {
      const int a = p >> 1, b = p & 1;
      const float o0 = lrelu(acc[p][i][0] + bv0);
      const float o1 = lrelu(acc[p][i][1] + bv1);
      colS[0] += o0; colQ[0] += o0 * o0;
      colS[1] += o1; colQ[1] += o1 * o1;
      *(float2*)&Y[(((size_t)n * OH + 2 * iy + a) * OH + 2 * ix + b) * 32 +
                   n0] = make_float2(o0, o1);
    }
  }
  const int rgrp = tid >> 4;
  __syncthreads();  // As/Bs dead; reuse red arrays safely after compute
  redS[rgrp][n0 + 0] = colS[0];
  redS[rgrp][n0 + 1] = colS[1];
  redQ[rgrp][n0 + 0] = colQ[0];
  redQ[rgrp][n0 + 1] = colQ[1];
  __syncthreads();
  if (tid < 32) {
    float S = 0.f, Q = 0.f;
#pragma unroll
    for (int r = 0; r < 16; ++r) {
      S += redS[r][tid];
      Q += redQ[r][tid];
    }
    atomicAdd(&stOut[tid], S);
    atomicAdd(&stOut[256 + tid], Q);
  }
}

// ======================= conv1 (CIN=3), NCHW in -> NHWC out ================
__global__ __launch_bounds__(256) void conv1(
    const float* __restrict__ x, const float* __restrict__ w,
    const float* __restrict__ bias, float* __restrict__ y,
    float* __restrict__ st) {
  __shared__ float lw[4 * 3 * 12];
  __shared__ float red[2][4][4];
  const int tid = threadIdx.x;
  const int cog = blockIdx.y * 4;
  for (int i = tid; i < 4 * 27; i += 256) {
    int cor = i / 27, rem = i % 27;
    lw[(cor * 3 + rem / 9) * 12 + rem % 9] = w[cog * 27 + i];
  }
  __syncthreads();
  const int idx = blockIdx.x * 256 + tid;
  const int q = idx & 255;
  const int n = idx >> 8;
  const int qy = q >> 4, qx = q & 15;
  const int iy0 = 4 * qy - 1, ix0 = 4 * qx - 1;
  const float* xn = x + (size_t)n * 3 * 4096;
  bool okr[5], okc[5];
#pragma unroll
  for (int r = 0; r < 5; ++r) okr[r] = (unsigned)(iy0 + r) < 64u;
#pragma unroll
  for (int c = 0; c < 5; ++c) okc[c] = (unsigned)(ix0 + c) < 64u;

  float acc[4][4];
#pragma unroll
  for (int j = 0; j < 4; ++j) {
    const float b = bias[cog + j];
#pragma unroll
    for (int p = 0; p < 4; ++p) acc[j][p] = b;
  }
#pragma unroll
  for (int ci = 0; ci < 3; ++ci) {
    const float* xp = xn + ci * 4096;
    float v[5][5];
#pragma unroll
    for (int r = 0; r < 5; ++r)
#pragma unroll
      for (int c = 0; c < 5; ++c)
        v[r][c] = (okr[r] && okc[c]) ? xp[(iy0 + r) * 64 + ix0 + c] : 0.f;
#pragma unroll
    for (int j = 0; j < 4; ++j) {
      const float* wj = &lw[(j * 3 + ci) * 12];
#pragma unroll
      for (int dy = 0; dy < 2; ++dy)
#pragma unroll
        for (int dx = 0; dx < 2; ++dx)
#pragma unroll
          for (int ky = 0; ky < 3; ++ky)
#pragma unroll
            for (int kx = 0; kx < 3; ++kx)
              acc[j][dy * 2 + dx] = fmaf(v[2 * dy + ky][2 * dx + kx],
                                         wj[ky * 3 + kx], acc[j][dy * 2 + dx]);
    }
  }
  const int wv = tid >> 6, ln = tid & 63;
  float sS[4], sQ[4];
#pragma unroll
  for (int j = 0; j < 4; ++j) { sS[j] = 0.f; sQ[j] = 0.f; }
#pragma unroll
  for (int dy = 0; dy < 2; ++dy)
#pragma unroll
    for (int dx = 0; dx < 2; ++dx) {
      float4 o;
      o.x = lrelu(acc[0][dy * 2 + dx]);
      o.y = lrelu(acc[1][dy * 2 + dx]);
      o.z = lrelu(acc[2][dy * 2 + dx]);
      o.w = lrelu(acc[3][dy * 2 + dx]);
      *(float4*)&y[(((size_t)n * 32 + 2 * qy + dy) * 32 + 2 * qx + dx) * 32 +
                   cog] = o;
      sS[0] += o.x; sS[1] += o.y; sS[2] += o.z; sS[3] += o.w;
      sQ[0] += o.x * o.x; sQ[1] += o.y * o.y;
      sQ[2] += o.z * o.z; sQ[3] += o.w * o.w;
    }
#pragma unroll
  for (int j = 0; j < 4; ++j) {
    float s_ = sS[j], q_ = sQ[j];
#pragma unroll
    for (int off = 32; off > 0; off >>= 1) {
      s_ += __shfl_down(s_, off);
      q_ += __shfl_down(q_, off);
    }
    if (ln == 0) { red[0][wv][j] = s_; red[1][wv][j] = q_; }
  }
  __syncthreads();
  if (tid < 4) {
    const int j = tid;
    float S = red[0][0][j] + red[0][1][j] + red[0][2][j] + red[0][3][j];
    float Q = red[1][0][j] + red[1][1][j] + red[1][2][j] + red[1][3][j];
    atomicAdd(&st[cog + j], S);
    atomicAdd(&st[256 + cog + j], Q);
  }
}

// ======================= final convT 3x3 s1 p1 + tanh, LDS-tiled ===========
__global__ __launch_bounds__(256) void convt4_tanh(
    const float* __restrict__ x, const float* __restrict__ w,
    const float* __restrict__ bias, const float* __restrict__ st, float invN,
    float* __restrict__ out) {
  __shared__ float tile[324 * 36];
  __shared__ float s0[32], s1[32];
  const int tid = threadIdx.x;
  for (int c = tid; c < 32; c += 256) {
    float m = st[c] * invN;
    float var = st[256 + c] * invN - m * m;
    float s = rsqrtf(var + EPS_BN);
    s0[c] = s;
    s1[c] = m * s;
  }
  __syncthreads();
  const int n = blockIdx.x >> 4;
  const int t16 = blockIdx.x & 15;
  const int oy0 = (t16 >> 2) * 16, ox0 = (t16 & 3) * 16;
  const float* xn = x + (size_t)n * 131072;
  for (int j = tid; j < 2592; j += 256) {
    const int px = j >> 3, cq = (j & 7) * 4;
    const int r = px / 18, c = px - r * 18;
    const int gy = oy0 - 1 + r, gx = ox0 - 1 + c;
    float4 v = make_float4(0.f, 0.f, 0.f, 0.f);
    if ((unsigned)gy < 64u && (unsigned)gx < 64u) {
      v = *(const float4*)&xn[(((size_t)gy << 6) + gx) * 32 + cq];
      v.x = fmaf(v.x, s0[cq + 0], -s1[cq + 0]);
      v.y = fmaf(v.y, s0[cq + 1], -s1[cq + 1]);
      v.z = fmaf(v.z, s0[cq + 2], -s1[cq + 2]);
      v.w = fmaf(v.w, s0[cq + 3], -s1[cq + 3]);
    }
    *(float4*)&tile[px * 36 + cq] = v;
  }
  __syncthreads();
  const int py = tid >> 4, pxx = tid & 15;
  float acc0 = bias[0], acc1 = bias[1], acc2 = bias[2];
  for (int cb4 = 0; cb4 < 8; ++cb4) {
    float4 wv[27];
    const float4* wp = (const float4*)(w + cb4 * 108);
#pragma unroll
    for (int q = 0; q < 27; ++q) wv[q] = wp[q];
    const float* wr = (const float*)wv;
#pragma unroll
    for (int ky = 0; ky < 3; ++ky)
#pragma unroll
      for (int kx = 0; kx < 3; ++kx) {
        const float4 v = *(const float4*)
            &tile[((py + 2 - ky) * 18 + (pxx + 2 - kx)) * 36 + cb4 * 4];
        const int tt = ky * 3 + kx;
#pragma unroll
        for (int u = 0; u < 4; ++u) {
          const float vi = (&v.x)[u];
          acc0 = fmaf(vi, wr[u * 27 + tt], acc0);
          acc1 = fmaf(vi, wr[u * 27 + 9 + tt], acc1);
          acc2 = fmaf(vi, wr[u * 27 + 18 + tt], acc2);
        }
      }
  }
  const int oy = oy0 + py, ox = ox0 + pxx;
  float* op = out + (size_t)n * 3 * 4096 + oy * 64 + ox;
  op[0] = 1.f / (1.f + __expf(-2.f * acc0));
  op[4096] = 1.f / (1.f + __expf(-2.f * acc1));
  op[8192] = 1.f / (1.f + __expf(-2.f * acc2));
}

// ======================= dense GEMM (fc / VQ distance) =====================
__global__ __launch_bounds__(256) void gemm_abt(
    const float* __restrict__ A, const float* __restrict__ B,
    const float* __restrict__ bias, const float* __restrict__ stA, float invN,
    float* __restrict__ C, float* __restrict__ P, int K, int ldc, int col0,
    float alpha, int act) {
  __shared__ float As[16][68];
  __shared__ float Bsh[16][68];
  __shared__ float nrm[2][256];
  const int tid = threadIdx.x;
  if (stA) {
    const int c = tid;
    float m = stA[c] * invN;
    float var = stA[256 + c] * invN - m * m;
    float s = rsqrtf(var + EPS_BN);
    nrm[0][c] = s;
    nrm[1][c] = m * s;
    __syncthreads();
  }
  const int lm = tid >> 2, lk = (tid & 3) << 2;
  const int KS = gridDim.z;
  const int kChunk = K / KS;
  const int kStart = blockIdx.z * kChunk;
  const float* Arow = A + (size_t)(blockIdx.y * 64 + lm) * K + lk;
  const float* Brow = B + (size_t)(blockIdx.x * 64 + lm) * K + lk;
  float acc[4][4] = {};
  const int m0 = (tid >> 4) << 2, n0 = (tid & 15) << 2;

  for (int k0 = kStart; k0 < kStart + kChunk; k0 += 16) {
    float4 av = *(const float4*)(Arow + k0);
    float4 bv = *(const float4*)(Brow + k0);
    if (stA) {
      const int ch = (k0 + lk) >> 4;
      const float s = nrm[0][ch], ms = nrm[1][ch];
      av.x = fmaf(av.x, s, -ms);
      av.y = fmaf(av.y, s, -ms);
      av.z = fmaf(av.z, s, -ms);
      av.w = fmaf(av.w, s, -ms);
    }
    As[lk + 0][lm] = av.x; As[lk + 1][lm] = av.y;
    As[lk + 2][lm] = av.z; As[lk + 3][lm] = av.w;
    Bsh[lk + 0][lm] = bv.x; Bsh[lk + 1][lm] = bv.y;
    Bsh[lk + 2][lm] = bv.z; Bsh[lk + 3][lm] = bv.w;
    __syncthreads();
#pragma unroll
    for (int kk = 0; kk < 16; ++kk) {
      const float4 a = *(const float4*)&As[kk][m0];
      const float4 b = *(const float4*)&Bsh[kk][n0];
      acc[0][0] = fmaf(a.x, b.x, acc[0][0]); acc[0][1] = fmaf(a.x, b.y, acc[0][1]);
      acc[0][2] = fmaf(a.x, b.z, acc[0][2]); acc[0][3] = fmaf(a.x, b.w, acc[0][3]);
      acc[1][0] = fmaf(a.y, b.x, acc[1][0]); acc[1][1] = fmaf(a.y, b.y, acc[1][1]);
      acc[1][2] = fmaf(a.y, b.z, acc[1][2]); acc[1][3] = fmaf(a.y, b.w, acc[1][3]);
      acc[2][0] = fmaf(a.z, b.x, acc[2][0]); acc[2][1] = fmaf(a.z, b.y, acc[2][1]);
      acc[2][2] = fmaf(a.z, b.z, acc[2][2]); acc[2][3] = fmaf(a.z, b.w, acc[2][3]);
      acc[3][0] = fmaf(a.w, b.x, acc[3][0]); acc[3][1] = fmaf(a.w, b.y, acc[3][1]);
      acc[3][2] = fmaf(a.w, b.z, acc[3][2]); acc[3][3] = fmaf(a.w, b.w, acc[3][3]);
    }
    __syncthreads();
  }

  const int gm = blockIdx.y * 64 + m0;
  const int gn = blockIdx.x * 64 + n0;
  if (KS == 1) {
#pragma unroll
    for (int i = 0; i < 4; ++i) {
      float4 o;
      o.x = alpha * acc[i][0] + bias[gn + 0];
      o.y = alpha * acc[i][1] + bias[gn + 1];
      o.z = alpha * acc[i][2] + bias[gn + 2];
      o.w = alpha * acc[i][3] + bias[gn + 3];
      if (act == 1) {
        o.x = fmaxf(o.x, 0.f); o.y = fmaxf(o.y, 0.f);
        o.z = fmaxf(o.z, 0.f); o.w = fmaxf(o.w, 0.f);
      }
      *(float4*)&C[(size_t)(gm + i) * ldc + col0 + gn] = o;
    }
  } else {
    const int M = gridDim.y * 64, N = gridDim.x * 64;
#pragma unroll
    for (int i = 0; i < 4; ++i)
      *(float4*)&P[((size_t)blockIdx.z * M + gm + i) * N + gn] =
          make_float4(acc[i][0], acc[i][1], acc[i][2], acc[i][3]);
  }
}

__global__ __launch_bounds__(256) void gemm_reduce(
    const float* __restrict__ P, float* __restrict__ C,
    const float* __restrict__ bias, int M, int N, int ldc, int col0,
    float alpha, int act, int KS) {
  const int idx = blockIdx.x * 256 + threadIdx.x;
  if (idx >= M * N) return;
  const int m = idx / N, n = idx % N;
  float s = 0.f;
  for (int z = 0; z < KS; ++z) s += P[((size_t)z * M + m) * N + n];
  float v = alpha * s + bias[n];
  if (act == 1) v = fmaxf(v, 0.f);
  C[(size_t)m * ldc + col0 + n] = v;
}

// ======================= VQ =================================================
__global__ __launch_bounds__(256) void rowsq(const float* __restrict__ cb,
                                             float* __restrict__ csq) {
  const int row = blockIdx.x * 4 + (threadIdx.x >> 6);
  const int ln = threadIdx.x & 63;
  const float4 v = ((const float4*)(cb + (size_t)row * 256))[ln];
  float s = v.x * v.x + v.y * v.y + v.z * v.z + v.w * v.w;
#pragma unroll
  for (int off = 32; off > 0; off >>= 1) s += __shfl_down(s, off);
  if (ln == 0) csq[row] = s;
}

__global__ __launch_bounds__(256) void argmin_d2(const float* __restrict__ d2,
                                                 int* __restrict__ idx) {
  const int b = blockIdx.x, t = threadIdx.x;
  const float* row = d2 + (size_t)b * 8192;
  float best = 3.4e38f;
  int bi = 0x7fffffff;
  for (int k = t; k < 8192; k += 256) {
    const float v = row[k];
    if (v < best) { best = v; bi = k; }
  }
  __shared__ float bval[256];
  __shared__ int bidx[256];
  bval[t] = best;
  bidx[t] = bi;
  __syncthreads();
  for (int s = 128; s > 0; s >>= 1) {
    if (t < s) {
      const float ov = bval[t + s];
      const int oi = bidx[t + s];
      if (ov < bval[t] || (ov == bval[t] && oi < bidx[t])) {
        bval[t] = ov;
        bidx[t] = oi;
      }
    }
    __syncthreads();
  }
  if (t == 0) idx[b] = bidx[0];
}

__global__ __launch_bounds__(256) void vq_gather_loss(
    const float* __restrict__ ze, const float* __restrict__ cb,
    const int* __restrict__ idx, float* __restrict__ zq,
    float* __restrict__ lossacc) {
  const int b = blockIdx.x, d = threadIdx.x;
  const int i = b * 256 + d;
  const float q = cb[(size_t)idx[b] * 256 + d];
  zq[i] = q;
  const float df = ze[i] - q;
  float v = df * df;
  __shared__ float sh[256];
  sh[d] = v;
  __syncthreads();
  for (int s = 128; s > 0; s >>= 1) {
    if (d < s) sh[d] += sh[d + s];
    __syncthreads();
  }
  if (d == 0) atomicAdd(lossacc, sh[0]);
}

__global__ void write_loss(const float* __restrict__ lossacc,
                           float* __restrict__ out) {
  out[0] = 2.f * lossacc[0];
}

// ---------------------------------------------------------------------------
extern "C" void kernel_launch(void* const* d_in, const int* in_sizes, int n_in,
                              void* d_out, int out_size, void* d_ws,
                              size_t ws_size, hipStream_t stream) {
  const float* x = (const float*)d_in[0];
  const float* ew1 = (const float*)d_in[1];
  const float* eb1 = (const float*)d_in[2];
  const float* ew2 = (const float*)d_in[3];
  const float* eb2 = (const float*)d_in[4];
  const float* ew3 = (const float*)d_in[5];
  const float* eb3 = (const float*)d_in[6];
  const float* ew4 = (const float*)d_in[7];
  const float* eb4 = (const float*)d_in[8];
  const float* wmu = (const float*)d_in[9];
  const float* bmu = (const float*)d_in[10];
  const float* wcov = (const float*)d_in[11];
  const float* bcov = (const float*)d_in[12];
  const float* cb = (const float*)d_in[13];
  const float* wfc = (const float*)d_in[14];
  const float* bfc = (const float*)d_in[15];
  const float* wt1 = (const float*)d_in[16];
  const float* bt1 = (const float*)d_in[17];
  const float* wt2 = (const float*)d_in[18];
  const float* bt2 = (const float*)d_in[19];
  const float* wt3 = (const float*)d_in[20];
  const float* bt3 = (const float*)d_in[21];
  const float* wt31 = (const float*)d_in[22];
  const float* bt31 = (const float*)d_in[23];
  const float* wt4 = (const float*)d_in[24];
  const float* bt4 = (const float*)d_in[25];

  float* ws = (float*)d_ws;
  float* a1 = ws;               // NHWC [256,32,32,32]  (reused as g3)
  float* a2 = a1 + 8388608;     // NHWC [256,16,16,64]  (reused as g2)
  float* a3 = a2 + 4194304;     // NHWC [256,8,8,128]   (reused as g1)
  float* a4 = a3 + 2097152;     // NHWC [256,4,4,256]   (reused as g0)
  float* g31 = a4 + 1048576;    // NHWC [256,64,64,32]  33554432
  float* d2 = g31;              // [256,8192]
  float* P = g31 + 2097152;     // 262144
  float* csq = g31 + 2359296;   // 8192
  float* a4n = g31 + 2367488;   // NCHW a4 copy, 1048576
  float* wfcT = g31 + 3416064;  // 1048576
  float* bfcT = g31 + 4464640;  // 4096
  float* wTc2 = g31 + 4468736;  // 18432
  float* wTc3 = g31 + 4487168;  // 73728
  float* wTc4 = g31 + 4560896;  // 294912
  float* ze = g31 + 33554432;   // [256,256]
  float* zq = ze + 65536;
  float* stats = zq + 65536;    // 8 layers x 512
  float* lossacc = stats + 4096;
  int* idx = (int*)(lossacc + 4);
  float* wTt1 = lossacc + 4 + 256;  // 294912 (parity layout)
  float* wTt2 = wTt1 + 294912;      // 73728  (parity layout)
  float* wTt3 = wTt2 + 73728;       // 18432  (tap-major, merged)
  float* wTt31 = wTt3 + 18432;      // 9216   (tap-major, merged)
  float* g3 = a1;
  float* g2 = a2;
  float* g1 = a3;
  float* g0 = a4;

  float* st0 = stats + 0 * 512;
  float* st1 = stats + 1 * 512;
  float* st2 = stats + 2 * 512;
  float* st3 = stats + 3 * 512;
  float* st4 = stats + 4 * 512;
  float* st5 = stats + 5 * 512;
  float* st6 = stats + 6 * 512;
  float* st7 = stats + 7 * 512;

  hipMemsetAsync(stats, 0, (4096 + 8) * sizeof(float), stream);

  // ---- weight transposes (independent of activations) ----
  tr_convw<<<72, 256, 0, stream>>>(ew2, wTc2, 32, 64, 18432);
  tr_convw<<<288, 256, 0, stream>>>(ew3, wTc3, 64, 128, 73728);
  tr_convw<<<1152, 256, 0, stream>>>(ew4, wTc4, 128, 256, 294912);
  tr_convtw<<<1152, 256, 0, stream>>>(wt1, wTt1, 256, 128, 294912);
  tr_convtw<<<288, 256, 0, stream>>>(wt2, wTt2, 128, 64, 73728);
  tr_convtw_m<<<72, 256, 0, stream>>>(wt3, wTt3, 64, 32, 18432);
  tr_convtw_m<<<36, 256, 0, stream>>>(wt31, wTt31, 32, 32, 9216);
  tr_fcdec<<<4096, 256, 0, stream>>>(wfc, bfc, wfcT, bfcT);
  rowsq<<<2048, 256, 0, stream>>>(cb, csq);

  // ---- encoder ----
  conv1<<<dim3(256, 8), 256, 0, stream>>>(x, ew1, eb1, a1, st0);
  gemmconv<64, 64, 0, 32, 32, 64, true><<<dim3(1, 1024), 256, 0, stream>>>(
      a1, wTc2, eb2, st0, 1.f / (256.f * 1024.f), a2, st1);
  gemmconv<64, 64, 0, 16, 64, 128, true><<<dim3(2, 256), 256, 0, stream>>>(
      a2, wTc3, eb3, st1, 1.f / (256.f * 256.f), a3, st2);
  gemmconv<32, 64, 0, 8, 128, 256, true><<<dim3(4, 128), 256, 0, stream>>>(
      a3, wTc4, eb4, st2, 1.f / (256.f * 64.f), a4, st3);
  tr_a4<<<4096, 256, 0, stream>>>(a4, a4n);

  // ---- encoder FC (NCHW a4, raw wmu/wcov, ch=k>>4) ----
  gemm_abt<<<dim3(2, 4, 8), 256, 0, stream>>>(a4n, wmu, nullptr, st3,
                                              1.f / 4096.f, nullptr, P, 4096,
                                              0, 0, 1.f, 0);
  gemm_reduce<<<128, 256, 0, stream>>>(P, ze, bmu, 256, 128, 256, 0, 1.f, 0, 8);
  gemm_abt<<<dim3(2, 4, 8), 256, 0, stream>>>(a4n, wcov, nullptr, st3,
                                              1.f / 4096.f, nullptr, P, 4096,
                                              0, 0, 1.f, 0);
  gemm_reduce<<<128, 256, 0, stream>>>(P, ze, bcov, 256, 128, 256, 128, 1.f, 1, 8);

  // ---- VQ ----
  gemm_abt<<<dim3(128, 4, 1), 256, 0, stream>>>(ze, cb, csq, nullptr, 0.f, d2,
                                                nullptr, 256, 8192, 0, -2.f, 0);
  argmin_d2<<<256, 256, 0, stream>>>(d2, idx);
  vq_gather_loss<<<256, 256, 0, stream>>>(ze, cb, idx, zq, lossacc);

  // ---- decoder FC (NHWC-permuted rows) ----
  gemm_abt<<<dim3(64, 4, 1), 256, 0, stream>>>(zq, wfcT, bfcT, nullptr, 0.f,
                                               g0, nullptr, 256, 4096, 0, 1.f, 0);

  // ---- decoder ----
  gemmconv<32, 64, 1, 4, 256, 128, false><<<dim3(2, 128, 4), 256, 0, stream>>>(
      g0, wTt1, bt1, nullptr, 0.f, g1, st4);
  gemmconv<64, 64, 1, 8, 128, 64, true><<<dim3(1, 256, 4), 256, 0, stream>>>(
      g1, wTt2, bt2, st4, 1.f / (256.f * 64.f), g2, st5);
  convt_merged<16, 64, true><<<dim3(1, 1024), 256, 0, stream>>>(
      g2, wTt3, bt3, st5, 1.f / (256.f * 256.f), g3, st6);
  convt_merged<32, 32, true><<<dim3(1, 4096), 256, 0, stream>>>(
      g3, wTt31, bt31, st6, 1.f / (256.f * 1024.f), g31, st7);

  convt4_tanh<<<4096, 256, 0, stream>>>(g31, wt4, bt4, st7,
                                        1.f / (256.f * 4096.f), (float*)d_out);
  write_loss<<<1, 1, 0, stream>>>(lossacc, (float*)d_out + 3145728);
}

// Round 8
// 827.003 us; speedup vs baseline: 1.0765x; 1.0765x over previous
//
#include <hip/hip_runtime.h>
#include <cmath>

// ---------------------------------------------------------------------------
// VQ-VAE forward. B=256, C=3, HW=64, D=256, K=8192, LAT=128
// R7: all 7 mid convs (conv2-4, t1-t31) moved to bf16 MFMA implicit GEMM
// (mfma_f32_16x16x32_bf16, fp32 accumulate): activations normalized+rounded
// to bf16 in the A-stage, weights pre-transposed to bf16 [co][k] rows.
// ConvT = 4 parity sub-GEMMs (blockIdx.z). fc/VQ/conv1/convt4 stay fp32
// (proven accurate). Epilogue: bias+LeakyReLU+BN-stat atomics, fp32.
// ---------------------------------------------------------------------------

#define EPS_BN 1e-5f
typedef unsigned short ushort;
typedef short short8 __attribute__((ext_vector_type(8)));
typedef float f32x4 __attribute__((ext_vector_type(4)));

__device__ __forceinline__ float lrelu(float v) { return v >= 0.f ? v : 0.01f * v; }
__device__ __forceinline__ ushort f2bf(float f) {
  unsigned u = __float_as_uint(f);
  return (ushort)((u + 0x7FFF + ((u >> 16) & 1)) >> 16);
}

// ======================= weight transposes (once per launch) ===============
// conv (COUT,CIN,3,3) -> bf16 [co][t*CIN+ci]
__global__ __launch_bounds__(256) void tr_convw_bf(const float* __restrict__ w,
                                                   ushort* __restrict__ wT,
                                                   int CIN, int COUT, int total) {
  int i = blockIdx.x * 256 + threadIdx.x;
  if (i >= total) return;
  int co = i / (9 * CIN);
  int r = i - co * 9 * CIN;
  int t = r / CIN, ci = r - t * CIN;
  wT[i] = f2bf(w[((size_t)co * CIN + ci) * 9 + t]);
}

// convT (CIN,COUT,3,3) -> bf16 parity-concat [p][co][k], k=(kyi*nx+kxi)*CIN+ci
__global__ __launch_bounds__(256) void tr_convtw_bf(const float* __restrict__ w,
                                                    ushort* __restrict__ wT,
                                                    int CIN, int COUT, int total) {
  int i = blockIdx.x * 256 + threadIdx.x;
  if (i >= total) return;
  const int cc = CIN * COUT;
  int p, base, Kp;
  if (i < cc) { p = 0; base = 0; Kp = CIN; }
  else if (i < 3 * cc) { p = 1; base = cc; Kp = 2 * CIN; }
  else if (i < 5 * cc) { p = 2; base = 3 * cc; Kp = 2 * CIN; }
  else { p = 3; base = 5 * cc; Kp = 4 * CIN; }
  const int r = i - base;
  const int co = r / Kp;
  const int q = r - co * Kp;
  const int tix = q / CIN, ci = q - (q / CIN) * CIN;
  const int py = p >> 1, px = p & 1;
  const int nx = px ? 2 : 1;
  const int kyi = tix / nx, kxi = tix - kyi * nx;
  const int ky = py ? (kyi == 0 ? 0 : 2) : 1;
  const int kx = px ? (kxi == 0 ? 0 : 2) : 1;
  wT[i] = f2bf(w[((size_t)ci * COUT + co) * 9 + ky * 3 + kx]);
}

// a4 NHWC [256,4,4,256] -> NCHW [256,256,4,4]
__global__ __launch_bounds__(256) void tr_a4(const float* __restrict__ in,
                                             float* __restrict__ out) {
  int i = blockIdx.x * 256 + threadIdx.x;
  int n = i >> 12, k = i & 4095;
  out[i] = in[(size_t)(n << 12) + ((k & 15) << 8) + (k >> 4)];
}

// wfc [4096,256] + bfc: permute ROWS from (c,y,x) to (y,x,c)
__global__ __launch_bounds__(256) void tr_fcdec(const float* __restrict__ in,
                                                const float* __restrict__ bin,
                                                float* __restrict__ out,
                                                float* __restrict__ bout) {
  int i = blockIdx.x * 256 + threadIdx.x;
  int k = i >> 8, d = i & 255;
  int kp = (k & 15) * 256 + (k >> 4);
  out[(size_t)kp * 256 + d] = in[i];
  if (d == 0) bout[kp] = bin[k];
}

// ======================= bf16 MFMA implicit-GEMM conv / convT ==============
// MODE 0: stride-2 conv 3x3 pad1 (rows = output px). MODE 1: convT parity
// sub-GEMM, blockIdx.z = parity (rows = input px). NHWC fp32 activations,
// bf16 LDS tiles [row][k], mfma_f32_16x16x32_bf16, fp32 epilogue.
template <int TN, int MODE, int IH, int CIN, int COUT, bool HASN>
__global__ __launch_bounds__(256) void mfmaconv(
    const float* __restrict__ X, const ushort* __restrict__ WT,
    const float* __restrict__ bias, const float* __restrict__ st, float invN,
    float* __restrict__ Y, float* __restrict__ stOut) {
  constexpr int OH = (MODE == 0) ? IH / 2 : 2 * IH;
  constexpr int NF = TN / 16;
  __shared__ short As[64][40];
  __shared__ short Bs[TN][40];
  __shared__ float nrm0[HASN ? CIN : 4], nrm1[HASN ? CIN : 4];
  __shared__ float redS[4][TN], redQ[4][TN];
  const int tid = threadIdx.x;
  const int wv = tid >> 6, lane = tid & 63;
  const int quad = lane >> 4, ln15 = tid & 15;
  if (HASN) {
    for (int c = tid; c < CIN; c += 256) {
      float m = st[c] * invN;
      float var = st[256 + c] * invN - m * m;
      float s = rsqrtf(var + EPS_BN);
      nrm0[c] = s;
      nrm1[c] = m * s;
    }
    __syncthreads();
  }
  int py = 0, px = 0, nx = 1, K = 9 * CIN;
  const ushort* W = WT;
  if (MODE == 1) {
    const int pz = blockIdx.z;
    py = pz >> 1;
    px = pz & 1;
    nx = px ? 2 : 1;
    const int ny = py ? 2 : 1;
    K = ny * nx * CIN;
    const int pre[4] = {0, 1, 3, 5};
    W = WT + (size_t)pre[pz] * CIN * COUT;
  }
  const int gyTM = blockIdx.y * 64;
  const int gxTN = blockIdx.x * TN;

  // A-stage thread coords (row fixed across k0)
  const int sm = tid & 63, skg = (tid >> 6) * 8;
  int baseNB, baseIY, baseIX;
  {
    const int gm = gyTM + sm;
    if (MODE == 0) {
      const int ni = gm / (OH * OH), r = gm % (OH * OH);
      baseNB = ni * IH * IH;
      baseIY = 2 * (r / OH) - 1;
      baseIX = 2 * (r % OH) - 1;
    } else {
      const int ni = gm / (IH * IH), r = gm % (IH * IH);
      baseNB = ni * IH * IH;
      baseIY = r / IH;
      baseIX = r % IH;
    }
  }
  f32x4 acc[NF];
#pragma unroll
  for (int f = 0; f < NF; ++f) acc[f] = (f32x4){0.f, 0.f, 0.f, 0.f};

  for (int k0 = 0; k0 < K; k0 += 32) {
    const int t = k0 / CIN;
    const int ci0 = k0 - t * CIN;
    int iy, ix;
    if (MODE == 0) {
      iy = baseIY + t / 3;
      ix = baseIX + (t - (t / 3) * 3);
    } else {
      const int kyi = t / nx, kxi = t - (t / nx) * nx;
      iy = baseIY + ((py && kyi == 0) ? 1 : 0);
      ix = baseIX + ((px && kxi == 0) ? 1 : 0);
    }
    // ---- A stage: 8 channels -> bf16 ----
    {
      const bool ok =
          ((unsigned)iy < (unsigned)IH) && ((unsigned)ix < (unsigned)IH);
      float4 va = make_float4(0.f, 0.f, 0.f, 0.f), vb = va;
      if (ok) {
        const float* xp = &X[((size_t)baseNB + iy * IH + ix) * CIN + ci0 + skg];
        va = *(const float4*)xp;
        vb = *(const float4*)(xp + 4);
        if (HASN) {
          const int c = ci0 + skg;
          va.x = fmaf(va.x, nrm0[c + 0], -nrm1[c + 0]);
          va.y = fmaf(va.y, nrm0[c + 1], -nrm1[c + 1]);
          va.z = fmaf(va.z, nrm0[c + 2], -nrm1[c + 2]);
          va.w = fmaf(va.w, nrm0[c + 3], -nrm1[c + 3]);
          vb.x = fmaf(vb.x, nrm0[c + 4], -nrm1[c + 4]);
          vb.y = fmaf(vb.y, nrm0[c + 5], -nrm1[c + 5]);
          vb.z = fmaf(vb.z, nrm0[c + 6], -nrm1[c + 6]);
          vb.w = fmaf(vb.w, nrm0[c + 7], -nrm1[c + 7]);
        }
      }
      short8 o;
      o[0] = (short)f2bf(va.x); o[1] = (short)f2bf(va.y);
      o[2] = (short)f2bf(va.z); o[3] = (short)f2bf(va.w);
      o[4] = (short)f2bf(vb.x); o[5] = (short)f2bf(vb.y);
      o[6] = (short)f2bf(vb.z); o[7] = (short)f2bf(vb.w);
      *(short8*)&As[sm][skg] = o;
    }
    // ---- B stage: bf16 weights, rows [co][k] ----
    if (tid < TN * 4) {
      const int bn = tid >> 2, bkg = (tid & 3) * 8;
      *(short8*)&Bs[bn][bkg] =
          *(const short8*)&W[(size_t)(gxTN + bn) * K + k0 + bkg];
    }
    __syncthreads();
    const short8 a = *(const short8*)&As[wv * 16 + ln15][quad * 8];
#pragma unroll
    for (int f = 0; f < NF; ++f) {
      const short8 b = *(const short8*)&Bs[f * 16 + ln15][quad * 8];
      acc[f] = __builtin_amdgcn_mfma_f32_16x16x32_bf16(a, b, acc[f], 0, 0, 0);
    }
    __syncthreads();
  }

  // ---- epilogue: bias + lrelu + store + BN stats ----
  size_t maddr[4];
#pragma unroll
  for (int r = 0; r < 4; ++r) {
    const int m = gyTM + wv * 16 + quad * 4 + r;
    if (MODE == 0) {
      const int ni = m / (OH * OH), rr = m % (OH * OH);
      maddr[r] = (((size_t)ni * OH + rr / OH) * OH + rr % OH) * COUT;
    } else {
      const int ni = m / (IH * IH), rr = m % (IH * IH);
      const int oy = 2 * (rr / IH) + py, ox = 2 * (rr % IH) + px;
      maddr[r] = (((size_t)ni * OH + oy) * OH + ox) * COUT;
    }
  }
#pragma unroll
  for (int f = 0; f < NF; ++f) {
    const int col = gxTN + f * 16 + ln15;
    const float bv = bias[col];
    float cS = 0.f, cQ = 0.f;
#pragma unroll
    for (int r = 0; r < 4; ++r) {
      const float o = lrelu(acc[f][r] + bv);
      cS += o;
      cQ += o * o;
      Y[maddr[r] + col] = o;
    }
    cS += __shfl_down(cS, 32); cS += __shfl_down(cS, 16);
    cQ += __shfl_down(cQ, 32); cQ += __shfl_down(cQ, 16);
    if (lane < 16) { redS[wv][f * 16 + ln15] = cS; redQ[wv][f * 16 + ln15] = cQ; }
  }
  __syncthreads();
  if (tid < TN) {
    float S = redS[0][tid] + redS[1][tid] + redS[2][tid] + redS[3][tid];
    float Q = redQ[0][tid] + redQ[1][tid] + redQ[2][tid] + redQ[3][tid];
    atomicAdd(&stOut[gxTN + tid], S);
    atomicAdd(&stOut[256 + gxTN + tid], Q);
  }
}

// ======================= conv1 (CIN=3), NCHW in -> NHWC out ================
__global__ __launch_bounds__(256) void conv1(
    const float* __restrict__ x, const float* __restrict__ w,
    const float* __restrict__ bias, float* __restrict__ y,
    float* __restrict__ st) {
  __shared__ float lw[4 * 3 * 12];
  __shared__ float red[2][4][4];
  const int tid = threadIdx.x;
  const int cog = blockIdx.y * 4;
  for (int i = tid; i < 4 * 27; i += 256) {
    int cor = i / 27, rem = i % 27;
    lw[(cor * 3 + rem / 9) * 12 + rem % 9] = w[cog * 27 + i];
  }
  __syncthreads();
  const int idx = blockIdx.x * 256 + tid;
  const int q = idx & 255;
  const int n = idx >> 8;
  const int qy = q >> 4, qx = q & 15;
  const int iy0 = 4 * qy - 1, ix0 = 4 * qx - 1;
  const float* xn = x + (size_t)n * 3 * 4096;
  bool okr[5], okc[5];
#pragma unroll
  for (int r = 0; r < 5; ++r) okr[r] = (unsigned)(iy0 + r) < 64u;
#pragma unroll
  for (int c = 0; c < 5; ++c) okc[c] = (unsigned)(ix0 + c) < 64u;

  float acc[4][4];
#pragma unroll
  for (int j = 0; j < 4; ++j) {
    const float b = bias[cog + j];
#pragma unroll
    for (int p = 0; p < 4; ++p) acc[j][p] = b;
  }
#pragma unroll
  for (int ci = 0; ci < 3; ++ci) {
    const float* xp = xn + ci * 4096;
    float v[5][5];
#pragma unroll
    for (int r = 0; r < 5; ++r)
#pragma unroll
      for (int c = 0; c < 5; ++c)
        v[r][c] = (okr[r] && okc[c]) ? xp[(iy0 + r) * 64 + ix0 + c] : 0.f;
#pragma unroll
    for (int j = 0; j < 4; ++j) {
      const float* wj = &lw[(j * 3 + ci) * 12];
#pragma unroll
      for (int dy = 0; dy < 2; ++dy)
#pragma unroll
        for (int dx = 0; dx < 2; ++dx)
#pragma unroll
          for (int ky = 0; ky < 3; ++ky)
#pragma unroll
            for (int kx = 0; kx < 3; ++kx)
              acc[j][dy * 2 + dx] = fmaf(v[2 * dy + ky][2 * dx + kx],
                                         wj[ky * 3 + kx], acc[j][dy * 2 + dx]);
    }
  }
  const int wv = tid >> 6, ln = tid & 63;
  float sS[4], sQ[4];
#pragma unroll
  for (int j = 0; j < 4; ++j) { sS[j] = 0.f; sQ[j] = 0.f; }
#pragma unroll
  for (int dy = 0; dy < 2; ++dy)
#pragma unroll
    for (int dx = 0; dx < 2; ++dx) {
      float4 o;
      o.x = lrelu(acc[0][dy * 2 + dx]);
      o.y = lrelu(acc[1][dy * 2 + dx]);
      o.z = lrelu(acc[2][dy * 2 + dx]);
      o.w = lrelu(acc[3][dy * 2 + dx]);
      *(float4*)&y[(((size_t)n * 32 + 2 * qy + dy) * 32 + 2 * qx + dx) * 32 +
                   cog] = o;
      sS[0] += o.x; sS[1] += o.y; sS[2] += o.z; sS[3] += o.w;
      sQ[0] += o.x * o.x; sQ[1] += o.y * o.y;
      sQ[2] += o.z * o.z; sQ[3] += o.w * o.w;
    }
#pragma unroll
  for (int j = 0; j < 4; ++j) {
    float s_ = sS[j], q_ = sQ[j];
#pragma unroll
    for (int off = 32; off > 0; off >>= 1) {
      s_ += __shfl_down(s_, off);
      q_ += __shfl_down(q_, off);
    }
    if (ln == 0) { red[0][wv][j] = s_; red[1][wv][j] = q_; }
  }
  __syncthreads();
  if (tid < 4) {
    const int j = tid;
    float S = red[0][0][j] + red[0][1][j] + red[0][2][j] + red[0][3][j];
    float Q = red[1][0][j] + red[1][1][j] + red[1][2][j] + red[1][3][j];
    atomicAdd(&st[cog + j], S);
    atomicAdd(&st[256 + cog + j], Q);
  }
}

// ======================= final convT 3x3 s1 p1 + tanh, LDS-tiled ===========
__global__ __launch_bounds__(256) void convt4_tanh(
    const float* __restrict__ x, const float* __restrict__ w,
    const float* __restrict__ bias, const float* __restrict__ st, float invN,
    float* __restrict__ out) {
  __shared__ float tile[324 * 36];
  __shared__ float s0[32], s1[32];
  const int tid = threadIdx.x;
  for (int c = tid; c < 32; c += 256) {
    float m = st[c] * invN;
    float var = st[256 + c] * invN - m * m;
    float s = rsqrtf(var + EPS_BN);
    s0[c] = s;
    s1[c] = m * s;
  }
  __syncthreads();
  const int n = blockIdx.x >> 4;
  const int t16 = blockIdx.x & 15;
  const int oy0 = (t16 >> 2) * 16, ox0 = (t16 & 3) * 16;
  const float* xn = x + (size_t)n * 131072;
  for (int j = tid; j < 2592; j += 256) {
    const int px = j >> 3, cq = (j & 7) * 4;
    const int r = px / 18, c = px - r * 18;
    const int gy = oy0 - 1 + r, gx = ox0 - 1 + c;
    float4 v = make_float4(0.f, 0.f, 0.f, 0.f);
    if ((unsigned)gy < 64u && (unsigned)gx < 64u) {
      v = *(const float4*)&xn[(((size_t)gy << 6) + gx) * 32 + cq];
      v.x = fmaf(v.x, s0[cq + 0], -s1[cq + 0]);
      v.y = fmaf(v.y, s0[cq + 1], -s1[cq + 1]);
      v.z = fmaf(v.z, s0[cq + 2], -s1[cq + 2]);
      v.w = fmaf(v.w, s0[cq + 3], -s1[cq + 3]);
    }
    *(float4*)&tile[px * 36 + cq] = v;
  }
  __syncthreads();
  const int py = tid >> 4, pxx = tid & 15;
  float acc0 = bias[0], acc1 = bias[1], acc2 = bias[2];
  for (int cb4 = 0; cb4 < 8; ++cb4) {
    float4 wv[27];
    const float4* wp = (const float4*)(w + cb4 * 108);
#pragma unroll
    for (int q = 0; q < 27; ++q) wv[q] = wp[q];
    const float* wr = (const float*)wv;
#pragma unroll
    for (int ky = 0; ky < 3; ++ky)
#pragma unroll
      for (int kx = 0; kx < 3; ++kx) {
        const float4 v = *(const float4*)
            &tile[((py + 2 - ky) * 18 + (pxx + 2 - kx)) * 36 + cb4 * 4];
        const int tt = ky * 3 + kx;
#pragma unroll
        for (int u = 0; u < 4; ++u) {
          const float vi = (&v.x)[u];
          acc0 = fmaf(vi, wr[u * 27 + tt], acc0);
          acc1 = fmaf(vi, wr[u * 27 + 9 + tt], acc1);
          acc2 = fmaf(vi, wr[u * 27 + 18 + tt], acc2);
        }
      }
  }
  const int oy = oy0 + py, ox = ox0 + pxx;
  float* op = out + (size_t)n * 3 * 4096 + oy * 64 + ox;
  op[0] = 1.f / (1.f + __expf(-2.f * acc0));
  op[4096] = 1.f / (1.f + __expf(-2.f * acc1));
  op[8192] = 1.f / (1.f + __expf(-2.f * acc2));
}

// ======================= dense GEMM (fc / VQ distance), fp32 ===============
__global__ __launch_bounds__(256) void gemm_abt(
    const float* __restrict__ A, const float* __restrict__ B,
    const float* __restrict__ bias, const float* __restrict__ stA, float invN,
    float* __restrict__ C, float* __restrict__ P, int K, int ldc, int col0,
    float alpha, int act) {
  __shared__ float As[16][68];
  __shared__ float Bsh[16][68];
  __shared__ float nrm[2][256];
  const int tid = threadIdx.x;
  if (stA) {
    const int c = tid;
    float m = stA[c] * invN;
    float var = stA[256 + c] * invN - m * m;
    float s = rsqrtf(var + EPS_BN);
    nrm[0][c] = s;
    nrm[1][c] = m * s;
    __syncthreads();
  }
  const int lm = tid >> 2, lk = (tid & 3) << 2;
  const int KS = gridDim.z;
  const int kChunk = K / KS;
  const int kStart = blockIdx.z * kChunk;
  const float* Arow = A + (size_t)(blockIdx.y * 64 + lm) * K + lk;
  const float* Brow = B + (size_t)(blockIdx.x * 64 + lm) * K + lk;
  float acc[4][4] = {};
  const int m0 = (tid >> 4) << 2, n0 = (tid & 15) << 2;

  for (int k0 = kStart; k0 < kStart + kChunk; k0 += 16) {
    float4 av = *(const float4*)(Arow + k0);
    float4 bv = *(const float4*)(Brow + k0);
    if (stA) {
      const int ch = (k0 + lk) >> 4;
      const float s = nrm[0][ch], ms = nrm[1][ch];
      av.x = fmaf(av.x, s, -ms);
      av.y = fmaf(av.y, s, -ms);
      av.z = fmaf(av.z, s, -ms);
      av.w = fmaf(av.w, s, -ms);
    }
    As[lk + 0][lm] = av.x; As[lk + 1][lm] = av.y;
    As[lk + 2][lm] = av.z; As[lk + 3][lm] = av.w;
    Bsh[lk + 0][lm] = bv.x; Bsh[lk + 1][lm] = bv.y;
    Bsh[lk + 2][lm] = bv.z; Bsh[lk + 3][lm] = bv.w;
    __syncthreads();
#pragma unroll
    for (int kk = 0; kk < 16; ++kk) {
      const float4 a = *(const float4*)&As[kk][m0];
      const float4 b = *(const float4*)&Bsh[kk][n0];
      acc[0][0] = fmaf(a.x, b.x, acc[0][0]); acc[0][1] = fmaf(a.x, b.y, acc[0][1]);
      acc[0][2] = fmaf(a.x, b.z, acc[0][2]); acc[0][3] = fmaf(a.x, b.w, acc[0][3]);
      acc[1][0] = fmaf(a.y, b.x, acc[1][0]); acc[1][1] = fmaf(a.y, b.y, acc[1][1]);
      acc[1][2] = fmaf(a.y, b.z, acc[1][2]); acc[1][3] = fmaf(a.y, b.w, acc[1][3]);
      acc[2][0] = fmaf(a.z, b.x, acc[2][0]); acc[2][1] = fmaf(a.z, b.y, acc[2][1]);
      acc[2][2] = fmaf(a.z, b.z, acc[2][2]); acc[2][3] = fmaf(a.z, b.w, acc[2][3]);
      acc[3][0] = fmaf(a.w, b.x, acc[3][0]); acc[3][1] = fmaf(a.w, b.y, acc[3][1]);
      acc[3][2] = fmaf(a.w, b.z, acc[3][2]); acc[3][3] = fmaf(a.w, b.w, acc[3][3]);
    }
    __syncthreads();
  }

  const int gm = blockIdx.y * 64 + m0;
  const int gn = blockIdx.x * 64 + n0;
  if (KS == 1) {
#pragma unroll
    for (int i = 0; i < 4; ++i) {
      float4 o;
      o.x = alpha * acc[i][0] + bias[gn + 0];
      o.y = alpha * acc[i][1] + bias[gn + 1];
      o.z = alpha * acc[i][2] + bias[gn + 2];
      o.w = alpha * acc[i][3] + bias[gn + 3];
      if (act == 1) {
        o.x = fmaxf(o.x, 0.f); o.y = fmaxf(o.y, 0.f);
        o.z = fmaxf(o.z, 0.f); o.w = fmaxf(o.w, 0.f);
      }
      *(float4*)&C[(size_t)(gm + i) * ldc + col0 + gn] = o;
    }
  } else {
    const int M = gridDim.y * 64, N = gridDim.x * 64;
#pragma unroll
    for (int i = 0; i < 4; ++i)
      *(float4*)&P[((size_t)blockIdx.z * M + gm + i) * N + gn] =
          make_float4(acc[i][0], acc[i][1], acc[i][2], acc[i][3]);
  }
}

__global__ __launch_bounds__(256) void gemm_reduce(
    const float* __restrict__ P, float* __restrict__ C,
    const float* __restrict__ bias, int M, int N, int ldc, int col0,
    float alpha, int act, int KS) {
  const int idx = blockIdx.x * 256 + threadIdx.x;
  if (idx >= M * N) return;
  const int m = idx / N, n = idx % N;
  float s = 0.f;
  for (int z = 0; z < KS; ++z) s += P[((size_t)z * M + m) * N + n];
  float v = alpha * s + bias[n];
  if (act == 1) v = fmaxf(v, 0.f);
  C[(size_t)m * ldc + col0 + n] = v;
}

// ======================= VQ =================================================
__global__ __launch_bounds__(256) void rowsq(const float* __restrict__ cb,
                                             float* __restrict__ csq) {
  const int row = blockIdx.x * 4 + (threadIdx.x >> 6);
  const int ln = threadIdx.x & 63;
  const float4 v = ((const float4*)(cb + (size_t)row * 256))[ln];
  float s = v.x * v.x + v.y * v.y + v.z * v.z + v.w * v.w;
#pragma unroll
  for (int off = 32; off > 0; off >>= 1) s += __shfl_down(s, off);
  if (ln == 0) csq[row] = s;
}

__global__ __launch_bounds__(256) void argmin_d2(const float* __restrict__ d2,
                                                 int* __restrict__ idx) {
  const int b = blockIdx.x, t = threadIdx.x;
  const float* row = d2 + (size_t)b * 8192;
  float best = 3.4e38f;
  int bi = 0x7fffffff;
  for (int k = t; k < 8192; k += 256) {
    const float v = row[k];
    if (v < best) { best = v; bi = k; }
  }
  __shared__ float bval[256];
  __shared__ int bidx[256];
  bval[t] = best;
  bidx[t] = bi;
  __syncthreads();
  for (int s = 128; s > 0; s >>= 1) {
    if (t < s) {
      const float ov = bval[t + s];
      const int oi = bidx[t + s];
      if (ov < bval[t] || (ov == bval[t] && oi < bidx[t])) {
        bval[t] = ov;
        bidx[t] = oi;
      }
    }
    __syncthreads();
  }
  if (t == 0) idx[b] = bidx[0];
}

__global__ __launch_bounds__(256) void vq_gather_loss(
    const float* __restrict__ ze, const float* __restrict__ cb,
    const int* __restrict__ idx, float* __restrict__ zq,
    float* __restrict__ lossacc) {
  const int b = blockIdx.x, d = threadIdx.x;
  const int i = b * 256 + d;
  const float q = cb[(size_t)idx[b] * 256 + d];
  zq[i] = q;
  const float df = ze[i] - q;
  float v = df * df;
  __shared__ float sh[256];
  sh[d] = v;
  __syncthreads();
  for (int s = 128; s > 0; s >>= 1) {
    if (d < s) sh[d] += sh[d + s];
    __syncthreads();
  }
  if (d == 0) atomicAdd(lossacc, sh[0]);
}

__global__ void write_loss(const float* __restrict__ lossacc,
                           float* __restrict__ out) {
  out[0] = 2.f * lossacc[0];
}

// ---------------------------------------------------------------------------
extern "C" void kernel_launch(void* const* d_in, const int* in_sizes, int n_in,
                              void* d_out, int out_size, void* d_ws,
                              size_t ws_size, hipStream_t stream) {
  const float* x = (const float*)d_in[0];
  const float* ew1 = (const float*)d_in[1];
  const float* eb1 = (const float*)d_in[2];
  const float* ew2 = (const float*)d_in[3];
  const float* eb2 = (const float*)d_in[4];
  const float* ew3 = (const float*)d_in[5];
  const float* eb3 = (const float*)d_in[6];
  const float* ew4 = (const float*)d_in[7];
  const float* eb4 = (const float*)d_in[8];
  const float* wmu = (const float*)d_in[9];
  const float* bmu = (const float*)d_in[10];
  const float* wcov = (const float*)d_in[11];
  const float* bcov = (const float*)d_in[12];
  const float* cb = (const float*)d_in[13];
  const float* wfc = (const float*)d_in[14];
  const float* bfc = (const float*)d_in[15];
  const float* wt1 = (const float*)d_in[16];
  const float* bt1 = (const float*)d_in[17];
  const float* wt2 = (const float*)d_in[18];
  const float* bt2 = (const float*)d_in[19];
  const float* wt3 = (const float*)d_in[20];
  const float* bt3 = (const float*)d_in[21];
  const float* wt31 = (const float*)d_in[22];
  const float* bt31 = (const float*)d_in[23];
  const float* wt4 = (const float*)d_in[24];
  const float* bt4 = (const float*)d_in[25];

  float* ws = (float*)d_ws;
  float* a1 = ws;               // NHWC [256,32,32,32]  (reused as g3)
  float* a2 = a1 + 8388608;     // NHWC [256,16,16,64]  (reused as g2)
  float* a3 = a2 + 4194304;     // NHWC [256,8,8,128]   (reused as g1)
  float* a4 = a3 + 2097152;     // NHWC [256,4,4,256]   (reused as g0)
  float* g31 = a4 + 1048576;    // NHWC [256,64,64,32]  33554432
  float* d2 = g31;              // [256,8192] (aliases g31, dead before t1)
  float* P = g31 + 2097152;     // 262144
  float* csq = g31 + 2359296;   // 8192
  float* a4n = g31 + 2367488;   // NCHW a4 copy, 1048576
  float* wfcT = g31 + 3416064;  // 1048576
  float* bfcT = g31 + 4464640;  // 4096
  ushort* wTc2 = (ushort*)(g31 + 4468736);  // 18432 bf16 (encoder-time only)
  ushort* wTc3 = (ushort*)(g31 + 4487168);  // 73728 bf16
  ushort* wTc4 = (ushort*)(g31 + 4560896);  // 294912 bf16
  float* ze = g31 + 33554432;   // [256,256]
  float* zq = ze + 65536;
  float* stats = zq + 65536;    // 8 layers x 512
  float* lossacc = stats + 4096;
  int* idx = (int*)(lossacc + 4);
  ushort* wTt1 = (ushort*)(lossacc + 4 + 256);  // 294912 bf16 (parity)
  ushort* wTt2 = wTt1 + 294912;                 // 73728 bf16
  ushort* wTt3 = wTt2 + 73728;                  // 18432 bf16
  ushort* wTt31 = wTt3 + 18432;                 // 9216 bf16
  float* g3 = a1;
  float* g2 = a2;
  float* g1 = a3;
  float* g0 = a4;

  float* st0 = stats + 0 * 512;
  float* st1 = stats + 1 * 512;
  float* st2 = stats + 2 * 512;
  float* st3 = stats + 3 * 512;
  float* st4 = stats + 4 * 512;
  float* st5 = stats + 5 * 512;
  float* st6 = stats + 6 * 512;
  float* st7 = stats + 7 * 512;

  hipMemsetAsync(stats, 0, (4096 + 8) * sizeof(float), stream);

  // ---- weight transposes (bf16) ----
  tr_convw_bf<<<72, 256, 0, stream>>>(ew2, wTc2, 32, 64, 18432);
  tr_convw_bf<<<288, 256, 0, stream>>>(ew3, wTc3, 64, 128, 73728);
  tr_convw_bf<<<1152, 256, 0, stream>>>(ew4, wTc4, 128, 256, 294912);
  tr_convtw_bf<<<1152, 256, 0, stream>>>(wt1, wTt1, 256, 128, 294912);
  tr_convtw_bf<<<288, 256, 0, stream>>>(wt2, wTt2, 128, 64, 73728);
  tr_convtw_bf<<<72, 256, 0, stream>>>(wt3, wTt3, 64, 32, 18432);
  tr_convtw_bf<<<36, 256, 0, stream>>>(wt31, wTt31, 32, 32, 9216);
  tr_fcdec<<<4096, 256, 0, stream>>>(wfc, bfc, wfcT, bfcT);
  rowsq<<<2048, 256, 0, stream>>>(cb, csq);

  // ---- encoder ----
  conv1<<<dim3(256, 8), 256, 0, stream>>>(x, ew1, eb1, a1, st0);
  mfmaconv<64, 0, 32, 32, 64, true><<<dim3(1, 1024), 256, 0, stream>>>(
      a1, wTc2, eb2, st0, 1.f / (256.f * 1024.f), a2, st1);
  mfmaconv<64, 0, 16, 64, 128, true><<<dim3(2, 256), 256, 0, stream>>>(
      a2, wTc3, eb3, st1, 1.f / (256.f * 256.f), a3, st2);
  mfmaconv<64, 0, 8, 128, 256, true><<<dim3(4, 64), 256, 0, stream>>>(
      a3, wTc4, eb4, st2, 1.f / (256.f * 64.f), a4, st3);
  tr_a4<<<4096, 256, 0, stream>>>(a4, a4n);

  // ---- encoder FC (fp32, NCHW a4, raw wmu/wcov, ch=k>>4) ----
  gemm_abt<<<dim3(2, 4, 8), 256, 0, stream>>>(a4n, wmu, nullptr, st3,
                                              1.f / 4096.f, nullptr, P, 4096,
                                              0, 0, 1.f, 0);
  gemm_reduce<<<128, 256, 0, stream>>>(P, ze, bmu, 256, 128, 256, 0, 1.f, 0, 8);
  gemm_abt<<<dim3(2, 4, 8), 256, 0, stream>>>(a4n, wcov, nullptr, st3,
                                              1.f / 4096.f, nullptr, P, 4096,
                                              0, 0, 1.f, 0);
  gemm_reduce<<<128, 256, 0, stream>>>(P, ze, bcov, 256, 128, 256, 128, 1.f, 1, 8);

  // ---- VQ (fp32) ----
  gemm_abt<<<dim3(128, 4, 1), 256, 0, stream>>>(ze, cb, csq, nullptr, 0.f, d2,
                                                nullptr, 256, 8192, 0, -2.f, 0);
  argmin_d2<<<256, 256, 0, stream>>>(d2, idx);
  vq_gather_loss<<<256, 256, 0, stream>>>(ze, cb, idx, zq, lossacc);

  // ---- decoder FC (fp32, NHWC-permuted rows) ----
  gemm_abt<<<dim3(64, 4, 1), 256, 0, stream>>>(zq, wfcT, bfcT, nullptr, 0.f,
                                               g0, nullptr, 256, 4096, 0, 1.f, 0);

  // ---- decoder (bf16 MFMA parity sub-GEMMs) ----
  mfmaconv<64, 1, 4, 256, 128, false><<<dim3(2, 64, 4), 256, 0, stream>>>(
      g0, wTt1, bt1, nullptr, 0.f, g1, st4);
  mfmaconv<64, 1, 8, 128, 64, true><<<dim3(1, 256, 4), 256, 0, stream>>>(
      g1, wTt2, bt2, st4, 1.f / (256.f * 64.f), g2, st5);
  mfmaconv<32, 1, 16, 64, 32, true><<<dim3(1, 1024, 4), 256, 0, stream>>>(
      g2, wTt3, bt3, st5, 1.f / (256.f * 256.f), g3, st6);
  mfmaconv<32, 1, 32, 32, 32, true><<<dim3(1, 4096, 4), 256, 0, stream>>>(
      g3, wTt31, bt31, st6, 1.f / (256.f * 1024.f), g31, st7);

  convt4_tanh<<<4096, 256, 0, stream>>>(g31, wt4, bt4, st7,
                                        1.f / (256.f * 4096.f), (float*)d_out);
  write_loss<<<1, 1, 0, stream>>>(lossacc, (float*)d_out + 3145728);
}

// Round 9
// 631.077 us; speedup vs baseline: 1.4107x; 1.3105x over previous
//
#include <hip/hip_runtime.h>
#include <cmath>

// ---------------------------------------------------------------------------
// VQ-VAE forward. B=256, C=3, HW=64, D=256, K=8192, LAT=128
// R8: t3/t31 convT rebuilt as halo-tile merged bf16-MFMA kernel (convt_mfma):
// one block = 64-px strip; (RSPAN+1)x(IH+1) zero-padded input tile staged
// ONCE (all 4 shifts index it via off=dy*(IH+1)+dx); all 9 taps' weights in
// LDS; 18/36 MFMAs with no intervening barriers; single epilogue+stats.
// conv2-4, t1, t2 keep R7 parity mfmaconv. fc/VQ/conv1/convt4 fp32.
// ---------------------------------------------------------------------------

#define EPS_BN 1e-5f
typedef unsigned short ushort;
typedef short short8 __attribute__((ext_vector_type(8)));
typedef float f32x4 __attribute__((ext_vector_type(4)));

__device__ __forceinline__ float lrelu(float v) { return v >= 0.f ? v : 0.01f * v; }
__device__ __forceinline__ ushort f2bf(float f) {
  unsigned u = __float_as_uint(f);
  return (ushort)((u + 0x7FFF + ((u >> 16) & 1)) >> 16);
}

// ======================= weight transposes (once per launch) ===============
// conv (COUT,CIN,3,3) -> bf16 [co][t*CIN+ci]
__global__ __launch_bounds__(256) void tr_convw_bf(const float* __restrict__ w,
                                                   ushort* __restrict__ wT,
                                                   int CIN, int COUT, int total) {
  int i = blockIdx.x * 256 + threadIdx.x;
  if (i >= total) return;
  int co = i / (9 * CIN);
  int r = i - co * 9 * CIN;
  int t = r / CIN, ci = r - t * CIN;
  wT[i] = f2bf(w[((size_t)co * CIN + ci) * 9 + t]);
}

// convT (CIN,COUT,3,3) -> bf16 parity-concat [p][co][k]
__global__ __launch_bounds__(256) void tr_convtw_bf(const float* __restrict__ w,
                                                    ushort* __restrict__ wT,
                                                    int CIN, int COUT, int total) {
  int i = blockIdx.x * 256 + threadIdx.x;
  if (i >= total) return;
  const int cc = CIN * COUT;
  int p, base, Kp;
  if (i < cc) { p = 0; base = 0; Kp = CIN; }
  else if (i < 3 * cc) { p = 1; base = cc; Kp = 2 * CIN; }
  else if (i < 5 * cc) { p = 2; base = 3 * cc; Kp = 2 * CIN; }
  else { p = 3; base = 5 * cc; Kp = 4 * CIN; }
  const int r = i - base;
  const int co = r / Kp;
  const int q = r - co * Kp;
  const int tix = q / CIN, ci = q - (q / CIN) * CIN;
  const int py = p >> 1, px = p & 1;
  const int nx = px ? 2 : 1;
  const int kyi = tix / nx, kxi = tix - kyi * nx;
  const int ky = py ? (kyi == 0 ? 0 : 2) : 1;
  const int kx = px ? (kxi == 0 ? 0 : 2) : 1;
  wT[i] = f2bf(w[((size_t)ci * COUT + co) * 9 + ky * 3 + kx]);
}

// convT (CIN,COUT,3,3) -> bf16 [t][co][ci] (tap-major for convt_mfma)
__global__ __launch_bounds__(256) void tr_convtw_tc(const float* __restrict__ w,
                                                    ushort* __restrict__ wT,
                                                    int CIN, int COUT, int total) {
  int i = blockIdx.x * 256 + threadIdx.x;
  if (i >= total) return;
  int ci = i % CIN;
  int tmp = i / CIN;
  int co = tmp % COUT;
  int t = tmp / COUT;
  wT[i] = f2bf(w[((size_t)ci * COUT + co) * 9 + t]);
}

// a4 NHWC [256,4,4,256] -> NCHW [256,256,4,4]
__global__ __launch_bounds__(256) void tr_a4(const float* __restrict__ in,
                                             float* __restrict__ out) {
  int i = blockIdx.x * 256 + threadIdx.x;
  int n = i >> 12, k = i & 4095;
  out[i] = in[(size_t)(n << 12) + ((k & 15) << 8) + (k >> 4)];
}

// wfc [4096,256] + bfc: permute ROWS from (c,y,x) to (y,x,c)
__global__ __launch_bounds__(256) void tr_fcdec(const float* __restrict__ in,
                                                const float* __restrict__ bin,
                                                float* __restrict__ out,
                                                float* __restrict__ bout) {
  int i = blockIdx.x * 256 + threadIdx.x;
  int k = i >> 8, d = i & 255;
  int kp = (k & 15) * 256 + (k >> 4);
  out[(size_t)kp * 256 + d] = in[i];
  if (d == 0) bout[kp] = bin[k];
}

// ======================= bf16 MFMA implicit-GEMM conv / convT ==============
template <int TN, int MODE, int IH, int CIN, int COUT, bool HASN>
__global__ __launch_bounds__(256) void mfmaconv(
    const float* __restrict__ X, const ushort* __restrict__ WT,
    const float* __restrict__ bias, const float* __restrict__ st, float invN,
    float* __restrict__ Y, float* __restrict__ stOut) {
  constexpr int OH = (MODE == 0) ? IH / 2 : 2 * IH;
  constexpr int NF = TN / 16;
  __shared__ short As[64][40];
  __shared__ short Bs[TN][40];
  __shared__ float nrm0[HASN ? CIN : 4], nrm1[HASN ? CIN : 4];
  __shared__ float redS[4][TN], redQ[4][TN];
  const int tid = threadIdx.x;
  const int wv = tid >> 6, lane = tid & 63;
  const int quad = lane >> 4, ln15 = tid & 15;
  if (HASN) {
    for (int c = tid; c < CIN; c += 256) {
      float m = st[c] * invN;
      float var = st[256 + c] * invN - m * m;
      float s = rsqrtf(var + EPS_BN);
      nrm0[c] = s;
      nrm1[c] = m * s;
    }
    __syncthreads();
  }
  int py = 0, px = 0, nx = 1, K = 9 * CIN;
  const ushort* W = WT;
  if (MODE == 1) {
    const int pz = blockIdx.z;
    py = pz >> 1;
    px = pz & 1;
    nx = px ? 2 : 1;
    const int ny = py ? 2 : 1;
    K = ny * nx * CIN;
    const int pre[4] = {0, 1, 3, 5};
    W = WT + (size_t)pre[pz] * CIN * COUT;
  }
  const int gyTM = blockIdx.y * 64;
  const int gxTN = blockIdx.x * TN;

  const int sm = tid & 63, skg = (tid >> 6) * 8;
  int baseNB, baseIY, baseIX;
  {
    const int gm = gyTM + sm;
    if (MODE == 0) {
      const int ni = gm / (OH * OH), r = gm % (OH * OH);
      baseNB = ni * IH * IH;
      baseIY = 2 * (r / OH) - 1;
      baseIX = 2 * (r % OH) - 1;
    } else {
      const int ni = gm / (IH * IH), r = gm % (IH * IH);
      baseNB = ni * IH * IH;
      baseIY = r / IH;
      baseIX = r % IH;
    }
  }
  f32x4 acc[NF];
#pragma unroll
  for (int f = 0; f < NF; ++f) acc[f] = (f32x4){0.f, 0.f, 0.f, 0.f};

  for (int k0 = 0; k0 < K; k0 += 32) {
    const int t = k0 / CIN;
    const int ci0 = k0 - t * CIN;
    int iy, ix;
    if (MODE == 0) {
      iy = baseIY + t / 3;
      ix = baseIX + (t - (t / 3) * 3);
    } else {
      const int kyi = t / nx, kxi = t - (t / nx) * nx;
      iy = baseIY + ((py && kyi == 0) ? 1 : 0);
      ix = baseIX + ((px && kxi == 0) ? 1 : 0);
    }
    {
      const bool ok =
          ((unsigned)iy < (unsigned)IH) && ((unsigned)ix < (unsigned)IH);
      float4 va = make_float4(0.f, 0.f, 0.f, 0.f), vb = va;
      if (ok) {
        const float* xp = &X[((size_t)baseNB + iy * IH + ix) * CIN + ci0 + skg];
        va = *(const float4*)xp;
        vb = *(const float4*)(xp + 4);
        if (HASN) {
          const int c = ci0 + skg;
          va.x = fmaf(va.x, nrm0[c + 0], -nrm1[c + 0]);
          va.y = fmaf(va.y, nrm0[c + 1], -nrm1[c + 1]);
          va.z = fmaf(va.z, nrm0[c + 2], -nrm1[c + 2]);
          va.w = fmaf(va.w, nrm0[c + 3], -nrm1[c + 3]);
          vb.x = fmaf(vb.x, nrm0[c + 4], -nrm1[c + 4]);
          vb.y = fmaf(vb.y, nrm0[c + 5], -nrm1[c + 5]);
          vb.z = fmaf(vb.z, nrm0[c + 6], -nrm1[c + 6]);
          vb.w = fmaf(vb.w, nrm0[c + 7], -nrm1[c + 7]);
        }
      }
      short8 o;
      o[0] = (short)f2bf(va.x); o[1] = (short)f2bf(va.y);
      o[2] = (short)f2bf(va.z); o[3] = (short)f2bf(va.w);
      o[4] = (short)f2bf(vb.x); o[5] = (short)f2bf(vb.y);
      o[6] = (short)f2bf(vb.z); o[7] = (short)f2bf(vb.w);
      *(short8*)&As[sm][skg] = o;
    }
    if (tid < TN * 4) {
      const int bn = tid >> 2, bkg = (tid & 3) * 8;
      *(short8*)&Bs[bn][bkg] =
          *(const short8*)&W[(size_t)(gxTN + bn) * K + k0 + bkg];
    }
    __syncthreads();
    const short8 a = *(const short8*)&As[wv * 16 + ln15][quad * 8];
#pragma unroll
    for (int f = 0; f < NF; ++f) {
      const short8 b = *(const short8*)&Bs[f * 16 + ln15][quad * 8];
      acc[f] = __builtin_amdgcn_mfma_f32_16x16x32_bf16(a, b, acc[f], 0, 0, 0);
    }
    __syncthreads();
  }

  size_t maddr[4];
#pragma unroll
  for (int r = 0; r < 4; ++r) {
    const int m = gyTM + wv * 16 + quad * 4 + r;
    if (MODE == 0) {
      const int ni = m / (OH * OH), rr = m % (OH * OH);
      maddr[r] = (((size_t)ni * OH + rr / OH) * OH + rr % OH) * COUT;
    } else {
      const int ni = m / (IH * IH), rr = m % (IH * IH);
      const int oy = 2 * (rr / IH) + py, ox = 2 * (rr % IH) + px;
      maddr[r] = (((size_t)ni * OH + oy) * OH + ox) * COUT;
    }
  }
#pragma unroll
  for (int f = 0; f < NF; ++f) {
    const int col = gxTN + f * 16 + ln15;
    const float bv = bias[col];
    float cS = 0.f, cQ = 0.f;
#pragma unroll
    for (int r = 0; r < 4; ++r) {
      const float o = lrelu(acc[f][r] + bv);
      cS += o;
      cQ += o * o;
      Y[maddr[r] + col] = o;
    }
    cS += __shfl_down(cS, 32); cS += __shfl_down(cS, 16);
    cQ += __shfl_down(cQ, 32); cQ += __shfl_down(cQ, 16);
    if (lane < 16) { redS[wv][f * 16 + ln15] = cS; redQ[wv][f * 16 + ln15] = cQ; }
  }
  __syncthreads();
  if (tid < TN) {
    float S = redS[0][tid] + redS[1][tid] + redS[2][tid] + redS[3][tid];
    float Q = redQ[0][tid] + redQ[1][tid] + redQ[2][tid] + redQ[3][tid];
    atomicAdd(&stOut[gxTN + tid], S);
    atomicAdd(&stOut[256 + gxTN + tid], Q);
  }
}

// ======================= halo-tile merged convT (COUT=32, CIN<=64) =========
// block = 64-px raster strip (rows of the implicit GEMM). Zero-padded halo
// tile (RSPAN+1)x(IH+1) staged once; all 4 shifts address it via
// off = dy*(IH+1)+dx (col IH / OOB rows hold zeros -> correct zero-pad).
// All 9 taps' weights in LDS; no barriers inside the MFMA loop.
template <int IH, int CIN, bool HASN>
__global__ __launch_bounds__(256) void convt_mfma(
    const float* __restrict__ X, const ushort* __restrict__ WT,
    const float* __restrict__ bias, const float* __restrict__ st, float invN,
    float* __restrict__ Y, float* __restrict__ stOut) {
  constexpr int OH = 2 * IH;
  constexpr int L = (IH == 32) ? 5 : 4;
  constexpr int RSPAN = 64 / IH;
  constexpr int NP = (RSPAN + 1) * (IH + 1);
  constexpr int LK = CIN + 8;
  __shared__ short As[NP][LK];
  __shared__ short Ws[9 * 32][LK];
  __shared__ float nrm0[HASN ? CIN : 4], nrm1[HASN ? CIN : 4];
  __shared__ float redS[4][32], redQ[4][32];
  const int tid = threadIdx.x;
  const int wv = tid >> 6, lane = tid & 63;
  const int quad = lane >> 4, ln15 = lane & 15;
  if (HASN) {
    for (int c = tid; c < CIN; c += 256) {
      float m = st[c] * invN;
      float var = st[256 + c] * invN - m * m;
      float s = rsqrtf(var + EPS_BN);
      nrm0[c] = s;
      nrm1[c] = m * s;
    }
  }
  // weights -> LDS ([t*32+co][ci])
  for (int i = tid; i < 9 * 32 * (CIN / 8); i += 256) {
    const int row = i / (CIN / 8), kg = (i % (CIN / 8)) * 8;
    *(short8*)&Ws[row][kg] = *(const short8*)&WT[(size_t)row * CIN + kg];
  }
  __syncthreads();  // nrm + Ws visible
  const int gy = blockIdx.x * 64;
  const int n = gy / (IH * IH);
  const int r0 = gy - n * (IH * IH);
  const int iy0 = r0 >> L;
  // halo tile -> LDS (normalized bf16, zero-padded)
  for (int i = tid; i < NP * (CIN / 8); i += 256) {
    const int slot = i / (CIN / 8), kg = (i % (CIN / 8)) * 8;
    const int ty = slot / (IH + 1), tx = slot - ty * (IH + 1);
    const int iy = iy0 + ty;
    short8 o = {0, 0, 0, 0, 0, 0, 0, 0};
    if (iy < IH && tx < IH) {
      const float* xp = &X[(((size_t)n * IH + iy) * IH + tx) * CIN + kg];
      float4 va = *(const float4*)xp, vb = *(const float4*)(xp + 4);
      if (HASN) {
        va.x = fmaf(va.x, nrm0[kg + 0], -nrm1[kg + 0]);
        va.y = fmaf(va.y, nrm0[kg + 1], -nrm1[kg + 1]);
        va.z = fmaf(va.z, nrm0[kg + 2], -nrm1[kg + 2]);
        va.w = fmaf(va.w, nrm0[kg + 3], -nrm1[kg + 3]);
        vb.x = fmaf(vb.x, nrm0[kg + 4], -nrm1[kg + 4]);
        vb.y = fmaf(vb.y, nrm0[kg + 5], -nrm1[kg + 5]);
        vb.z = fmaf(vb.z, nrm0[kg + 6], -nrm1[kg + 6]);
        vb.w = fmaf(vb.w, nrm0[kg + 7], -nrm1[kg + 7]);
      }
      o[0] = (short)f2bf(va.x); o[1] = (short)f2bf(va.y);
      o[2] = (short)f2bf(va.z); o[3] = (short)f2bf(va.w);
      o[4] = (short)f2bf(vb.x); o[5] = (short)f2bf(vb.y);
      o[6] = (short)f2bf(vb.z); o[7] = (short)f2bf(vb.w);
    }
    *(short8*)&As[slot][kg] = o;
  }
  __syncthreads();

  const int rA = wv * 16 + ln15;
  const int baseIdx = (rA >> L) * (IH + 1) + (rA & (IH - 1));
  f32x4 acc[4][2];
#pragma unroll
  for (int p = 0; p < 4; ++p)
#pragma unroll
    for (int f = 0; f < 2; ++f) acc[p][f] = (f32x4){0.f, 0.f, 0.f, 0.f};

  constexpr int NT[4] = {4, 2, 2, 1};
  constexpr int TT[4][4] = {{4, 5, 7, 8}, {3, 6, 0, 0}, {1, 2, 0, 0}, {0, 0, 0, 0}};
#pragma unroll
  for (int s = 0; s < 4; ++s) {
    const int off = (s >> 1) * (IH + 1) + (s & 1);
#pragma unroll
    for (int j = 0; j < NT[s]; ++j) {
      const int t = TT[s][j];
      const int ky = t / 3, kx = t - ky * 3;
      const int par = ((ky == 1) ? 0 : 2) + ((kx == 1) ? 0 : 1);
#pragma unroll
      for (int ks = 0; ks < CIN / 32; ++ks) {
        const short8 a =
            *(const short8*)&As[baseIdx + off][ks * 32 + quad * 8];
#pragma unroll
        for (int f = 0; f < 2; ++f) {
          const short8 b =
              *(const short8*)&Ws[t * 32 + f * 16 + ln15][ks * 32 + quad * 8];
          acc[par][f] =
              __builtin_amdgcn_mfma_f32_16x16x32_bf16(a, b, acc[par][f], 0, 0, 0);
        }
      }
    }
  }

  // epilogue
  const float bv0 = bias[ln15], bv1 = bias[16 + ln15];
  float cS[2] = {0.f, 0.f}, cQ[2] = {0.f, 0.f};
#pragma unroll
  for (int i = 0; i < 4; ++i) {
    const int rD = wv * 16 + quad * 4 + i;
    const int ry = rD >> L, rx = rD & (IH - 1);
    const int iy = iy0 + ry;
#pragma unroll
    for (int p = 0; p < 4; ++p) {
      const int a = p >> 1, b = p & 1;
      const size_t base = (((size_t)n * OH + 2 * iy + a) * OH + 2 * rx + b) * 32;
      {
        const float o = lrelu(acc[p][0][i] + bv0);
        cS[0] += o; cQ[0] += o * o;
        Y[base + ln15] = o;
      }
      {
        const float o = lrelu(acc[p][1][i] + bv1);
        cS[1] += o; cQ[1] += o * o;
        Y[base + 16 + ln15] = o;
      }
    }
  }
#pragma unroll
  for (int f = 0; f < 2; ++f) {
    float s_ = cS[f], q_ = cQ[f];
    s_ += __shfl_down(s_, 32); s_ += __shfl_down(s_, 16);
    q_ += __shfl_down(q_, 32); q_ += __shfl_down(q_, 16);
    if (lane < 16) { redS[wv][f * 16 + ln15] = s_; redQ[wv][f * 16 + ln15] = q_; }
  }
  __syncthreads();
  if (tid < 32) {
    float S = redS[0][tid] + redS[1][tid] + redS[2][tid] + redS[3][tid];
    float Q = redQ[0][tid] + redQ[1][tid] + redQ[2][tid] + redQ[3][tid];
    atomicAdd(&stOut[tid], S);
    atomicAdd(&stOut[256 + tid], Q);
  }
}

// ======================= conv1 (CIN=3), NCHW in -> NHWC out ================
__global__ __launch_bounds__(256) void conv1(
    const float* __restrict__ x, const float* __restrict__ w,
    const float* __restrict__ bias, float* __restrict__ y,
    float* __restrict__ st) {
  __shared__ float lw[4 * 3 * 12];
  __shared__ float red[2][4][4];
  const int tid = threadIdx.x;
  const int cog = blockIdx.y * 4;
  for (int i = tid; i < 4 * 27; i += 256) {
    int cor = i / 27, rem = i % 27;
    lw[(cor * 3 + rem / 9) * 12 + rem % 9] = w[cog * 27 + i];
  }
  __syncthreads();
  const int idx = blockIdx.x * 256 + tid;
  const int q = idx & 255;
  const int n = idx >> 8;
  const int qy = q >> 4, qx = q & 15;
  const int iy0 = 4 * qy - 1, ix0 = 4 * qx - 1;
  const float* xn = x + (size_t)n * 3 * 4096;
  bool okr[5], okc[5];
#pragma unroll
  for (int r = 0; r < 5; ++r) okr[r] = (unsigned)(iy0 + r) < 64u;
#pragma unroll
  for (int c = 0; c < 5; ++c) okc[c] = (unsigned)(ix0 + c) < 64u;

  float acc[4][4];
#pragma unroll
  for (int j = 0; j < 4; ++j) {
    const float b = bias[cog + j];
#pragma unroll
    for (int p = 0; p < 4; ++p) acc[j][p] = b;
  }
#pragma unroll
  for (int ci = 0; ci < 3; ++ci) {
    const float* xp = xn + ci * 4096;
    float v[5][5];
#pragma unroll
    for (int r = 0; r < 5; ++r)
#pragma unroll
      for (int c = 0; c < 5; ++c)
        v[r][c] = (okr[r] && okc[c]) ? xp[(iy0 + r) * 64 + ix0 + c] : 0.f;
#pragma unroll
    for (int j = 0; j < 4; ++j) {
      const float* wj = &lw[(j * 3 + ci) * 12];
#pragma unroll
      for (int dy = 0; dy < 2; ++dy)
#pragma unroll
        for (int dx = 0; dx < 2; ++dx)
#pragma unroll
          for (int ky = 0; ky < 3; ++ky)
#pragma unroll
            for (int kx = 0; kx < 3; ++kx)
              acc[j][dy * 2 + dx] = fmaf(v[2 * dy + ky][2 * dx + kx],
                                         wj[ky * 3 + kx], acc[j][dy * 2 + dx]);
    }
  }
  const int wv = tid >> 6, ln = tid & 63;
  float sS[4], sQ[4];
#pragma unroll
  for (int j = 0; j < 4; ++j) { sS[j] = 0.f; sQ[j] = 0.f; }
#pragma unroll
  for (int dy = 0; dy < 2; ++dy)
#pragma unroll
    for (int dx = 0; dx < 2; ++dx) {
      float4 o;
      o.x = lrelu(acc[0][dy * 2 + dx]);
      o.y = lrelu(acc[1][dy * 2 + dx]);
      o.z = lrelu(acc[2][dy * 2 + dx]);
      o.w = lrelu(acc[3][dy * 2 + dx]);
      *(float4*)&y[(((size_t)n * 32 + 2 * qy + dy) * 32 + 2 * qx + dx) * 32 +
                   cog] = o;
      sS[0] += o.x; sS[1] += o.y; sS[2] += o.z; sS[3] += o.w;
      sQ[0] += o.x * o.x; sQ[1] += o.y * o.y;
      sQ[2] += o.z * o.z; sQ[3] += o.w * o.w;
    }
#pragma unroll
  for (int j = 0; j < 4; ++j) {
    float s_ = sS[j], q_ = sQ[j];
#pragma unroll
    for (int off = 32; off > 0; off >>= 1) {
      s_ += __shfl_down(s_, off);
      q_ += __shfl_down(q_, off);
    }
    if (ln == 0) { red[0][wv][j] = s_; red[1][wv][j] = q_; }
  }
  __syncthreads();
  if (tid < 4) {
    const int j = tid;
    float S = red[0][0][j] + red[0][1][j] + red[0][2][j] + red[0][3][j];
    float Q = red[1][0][j] + red[1][1][j] + red[1][2][j] + red[1][3][j];
    atomicAdd(&st[cog + j], S);
    atomicAdd(&st[256 + cog + j], Q);
  }
}

// ======================= final convT 3x3 s1 p1 + tanh, LDS-tiled ===========
__global__ __launch_bounds__(256) void convt4_tanh(
    const float* __restrict__ x, const float* __restrict__ w,
    const float* __restrict__ bias, const float* __restrict__ st, float invN,
    float* __restrict__ out) {
  __shared__ float tile[324 * 36];
  __shared__ float s0[32], s1[32];
  const int tid = threadIdx.x;
  for (int c = tid; c < 32; c += 256) {
    float m = st[c] * invN;
    float var = st[256 + c] * invN - m * m;
    float s = rsqrtf(var + EPS_BN);
    s0[c] = s;
    s1[c] = m * s;
  }
  __syncthreads();
  const int n = blockIdx.x >> 4;
  const int t16 = blockIdx.x & 15;
  const int oy0 = (t16 >> 2) * 16, ox0 = (t16 & 3) * 16;
  const float* xn = x + (size_t)n * 131072;
  for (int j = tid; j < 2592; j += 256) {
    const int px = j >> 3, cq = (j & 7) * 4;
    const int r = px / 18, c = px - r * 18;
    const int gy = oy0 - 1 + r, gx = ox0 - 1 + c;
    float4 v = make_float4(0.f, 0.f, 0.f, 0.f);
    if ((unsigned)gy < 64u && (unsigned)gx < 64u) {
      v = *(const float4*)&xn[(((size_t)gy << 6) + gx) * 32 + cq];
      v.x = fmaf(v.x, s0[cq + 0], -s1[cq + 0]);
      v.y = fmaf(v.y, s0[cq + 1], -s1[cq + 1]);
      v.z = fmaf(v.z, s0[cq + 2], -s1[cq + 2]);
      v.w = fmaf(v.w, s0[cq + 3], -s1[cq + 3]);
    }
    *(float4*)&tile[px * 36 + cq] = v;
  }
  __syncthreads();
  const int py = tid >> 4, pxx = tid & 15;
  float acc0 = bias[0], acc1 = bias[1], acc2 = bias[2];
  for (int cb4 = 0; cb4 < 8; ++cb4) {
    float4 wv[27];
    const float4* wp = (const float4*)(w + cb4 * 108);
#pragma unroll
    for (int q = 0; q < 27; ++q) wv[q] = wp[q];
    const float* wr = (const float*)wv;
#pragma unroll
    for (int ky = 0; ky < 3; ++ky)
#pragma unroll
      for (int kx = 0; kx < 3; ++kx) {
        const float4 v = *(const float4*)
            &tile[((py + 2 - ky) * 18 + (pxx + 2 - kx)) * 36 + cb4 * 4];
        const int tt = ky * 3 + kx;
#pragma unroll
        for (int u = 0; u < 4; ++u) {
          const float vi = (&v.x)[u];
          acc0 = fmaf(vi, wr[u * 27 + tt], acc0);
          acc1 = fmaf(vi, wr[u * 27 + 9 + tt], acc1);
          acc2 = fmaf(vi, wr[u * 27 + 18 + tt], acc2);
        }
      }
  }
  const int oy = oy0 + py, ox = ox0 + pxx;
  float* op = out + (size_t)n * 3 * 4096 + oy * 64 + ox;
  op[0] = 1.f / (1.f + __expf(-2.f * acc0));
  op[4096] = 1.f / (1.f + __expf(-2.f * acc1));
  op[8192] = 1.f / (1.f + __expf(-2.f * acc2));
}

// ======================= dense GEMM (fc / VQ distance), fp32 ===============
__global__ __launch_bounds__(256) void gemm_abt(
    const float* __restrict__ A, const float* __restrict__ B,
    const float* __restrict__ bias, const float* __restrict__ stA, float invN,
    float* __restrict__ C, float* __restrict__ P, int K, int ldc, int col0,
    float alpha, int act) {
  __shared__ float As[16][68];
  __shared__ float Bsh[16][68];
  __shared__ float nrm[2][256];
  const int tid = threadIdx.x;
  if (stA) {
    const int c = tid;
    float m = stA[c] * invN;
    float var = stA[256 + c] * invN - m * m;
    float s = rsqrtf(var + EPS_BN);
    nrm[0][c] = s;
    nrm[1][c] = m * s;
    __syncthreads();
  }
  const int lm = tid >> 2, lk = (tid & 3) << 2;
  const int KS = gridDim.z;
  const int kChunk = K / KS;
  const int kStart = blockIdx.z * kChunk;
  const float* Arow = A + (size_t)(blockIdx.y * 64 + lm) * K + lk;
  const float* Brow = B + (size_t)(blockIdx.x * 64 + lm) * K + lk;
  float acc[4][4] = {};
  const int m0 = (tid >> 4) << 2, n0 = (tid & 15) << 2;

  for (int k0 = kStart; k0 < kStart + kChunk; k0 += 16) {
    float4 av = *(const float4*)(Arow + k0);
    float4 bv = *(const float4*)(Brow + k0);
    if (stA) {
      const int ch = (k0 + lk) >> 4;
      const float s = nrm[0][ch], ms = nrm[1][ch];
      av.x = fmaf(av.x, s, -ms);
      av.y = fmaf(av.y, s, -ms);
      av.z = fmaf(av.z, s, -ms);
      av.w = fmaf(av.w, s, -ms);
    }
    As[lk + 0][lm] = av.x; As[lk + 1][lm] = av.y;
    As[lk + 2][lm] = av.z; As[lk + 3][lm] = av.w;
    Bsh[lk + 0][lm] = bv.x; Bsh[lk + 1][lm] = bv.y;
    Bsh[lk + 2][lm] = bv.z; Bsh[lk + 3][lm] = bv.w;
    __syncthreads();
#pragma unroll
    for (int kk = 0; kk < 16; ++kk) {
      const float4 a = *(const float4*)&As[kk][m0];
      const float4 b = *(const float4*)&Bsh[kk][n0];
      acc[0][0] = fmaf(a.x, b.x, acc[0][0]); acc[0][1] = fmaf(a.x, b.y, acc[0][1]);
      acc[0][2] = fmaf(a.x, b.z, acc[0][2]); acc[0][3] = fmaf(a.x, b.w, acc[0][3]);
      acc[1][0] = fmaf(a.y, b.x, acc[1][0]); acc[1][1] = fmaf(a.y, b.y, acc[1][1]);
      acc[1][2] = fmaf(a.y, b.z, acc[1][2]); acc[1][3] = fmaf(a.y, b.w, acc[1][3]);
      acc[2][0] = fmaf(a.z, b.x, acc[2][0]); acc[2][1] = fmaf(a.z, b.y, acc[2][1]);
      acc[2][2] = fmaf(a.z, b.z, acc[2][2]); acc[2][3] = fmaf(a.z, b.w, acc[2][3]);
      acc[3][0] = fmaf(a.w, b.x, acc[3][0]); acc[3][1] = fmaf(a.w, b.y, acc[3][1]);
      acc[3][2] = fmaf(a.w, b.z, acc[3][2]); acc[3][3] = fmaf(a.w, b.w, acc[3][3]);
    }
    __syncthreads();
  }

  const int gm = blockIdx.y * 64 + m0;
  const int gn = blockIdx.x * 64 + n0;
  if (KS == 1) {
#pragma unroll
    for (int i = 0; i < 4; ++i) {
      float4 o;
      o.x = alpha * acc[i][0] + bias[gn + 0];
      o.y = alpha * acc[i][1] + bias[gn + 1];
      o.z = alpha * acc[i][2] + bias[gn + 2];
      o.w = alpha * acc[i][3] + bias[gn + 3];
      if (act == 1) {
        o.x = fmaxf(o.x, 0.f); o.y = fmaxf(o.y, 0.f);
        o.z = fmaxf(o.z, 0.f); o.w = fmaxf(o.w, 0.f);
      }
      *(float4*)&C[(size_t)(gm + i) * ldc + col0 + gn] = o;
    }
  } else {
    const int M = gridDim.y * 64, N = gridDim.x * 64;
#pragma unroll
    for (int i = 0; i < 4; ++i)
      *(float4*)&P[((size_t)blockIdx.z * M + gm + i) * N + gn] =
          make_float4(acc[i][0], acc[i][1], acc[i][2], acc[i][3]);
  }
}

__global__ __launch_bounds__(256) void gemm_reduce(
    const float* __restrict__ P, float* __restrict__ C,
    const float* __restrict__ bias, int M, int N, int ldc, int col0,
    float alpha, int act, int KS) {
  const int idx = blockIdx.x * 256 + threadIdx.x;
  if (idx >= M * N) return;
  const int m = idx / N, n = idx % N;
  float s = 0.f;
  for (int z = 0; z < KS; ++z) s += P[((size_t)z * M + m) * N + n];
  float v = alpha * s + bias[n];
  if (act == 1) v = fmaxf(v, 0.f);
  C[(size_t)m * ldc + col0 + n] = v;
}

// ======================= VQ =================================================
__global__ __launch_bounds__(256) void rowsq(const float* __restrict__ cb,
                                             float* __restrict__ csq) {
  const int row = blockIdx.x * 4 + (threadIdx.x >> 6);
  const int ln = threadIdx.x & 63;
  const float4 v = ((const float4*)(cb + (size_t)row * 256))[ln];
  float s = v.x * v.x + v.y * v.y + v.z * v.z + v.w * v.w;
#pragma unroll
  for (int off = 32; off > 0; off >>= 1) s += __shfl_down(s, off);
  if (ln == 0) csq[row] = s;
}

__global__ __launch_bounds__(256) void argmin_d2(const float* __restrict__ d2,
                                                 int* __restrict__ idx) {
  const int b = blockIdx.x, t = threadIdx.x;
  const float* row = d2 + (size_t)b * 8192;
  float best = 3.4e38f;
  int bi = 0x7fffffff;
  for (int k = t; k < 8192; k += 256) {
    const float v = row[k];
    if (v < best) { best = v; bi = k; }
  }
  __shared__ float bval[256];
  __shared__ int bidx[256];
  bval[t] = best;
  bidx[t] = bi;
  __syncthreads();
  for (int s = 128; s > 0; s >>= 1) {
    if (t < s) {
      const float ov = bval[t + s];
      const int oi = bidx[t + s];
      if (ov < bval[t] || (ov == bval[t] && oi < bidx[t])) {
        bval[t] = ov;
        bidx[t] = oi;
      }
    }
    __syncthreads();
  }
  if (t == 0) idx[b] = bidx[0];
}

__global__ __launch_bounds__(256) void vq_gather_loss(
    const float* __restrict__ ze, const float* __restrict__ cb,
    const int* __restrict__ idx, float* __restrict__ zq,
    float* __restrict__ lossacc) {
  const int b = blockIdx.x, d = threadIdx.x;
  const int i = b * 256 + d;
  const float q = cb[(size_t)idx[b] * 256 + d];
  zq[i] = q;
  const float df = ze[i] - q;
  float v = df * df;
  __shared__ float sh[256];
  sh[d] = v;
  __syncthreads();
  for (int s = 128; s > 0; s >>= 1) {
    if (d < s) sh[d] += sh[d + s];
    __syncthreads();
  }
  if (d == 0) atomicAdd(lossacc, sh[0]);
}

__global__ void write_loss(const float* __restrict__ lossacc,
                           float* __restrict__ out) {
  out[0] = 2.f * lossacc[0];
}

// ---------------------------------------------------------------------------
extern "C" void kernel_launch(void* const* d_in, const int* in_sizes, int n_in,
                              void* d_out, int out_size, void* d_ws,
                              size_t ws_size, hipStream_t stream) {
  const float* x = (const float*)d_in[0];
  const float* ew1 = (const float*)d_in[1];
  const float* eb1 = (const float*)d_in[2];
  const float* ew2 = (const float*)d_in[3];
  const float* eb2 = (const float*)d_in[4];
  const float* ew3 = (const float*)d_in[5];
  const float* eb3 = (const float*)d_in[6];
  const float* ew4 = (const float*)d_in[7];
  const float* eb4 = (const float*)d_in[8];
  const float* wmu = (const float*)d_in[9];
  const float* bmu = (const float*)d_in[10];
  const float* wcov = (const float*)d_in[11];
  const float* bcov = (const float*)d_in[12];
  const float* cb = (const float*)d_in[13];
  const float* wfc = (const float*)d_in[14];
  const float* bfc = (const float*)d_in[15];
  const float* wt1 = (const float*)d_in[16];
  const float* bt1 = (const float*)d_in[17];
  const float* wt2 = (const float*)d_in[18];
  const float* bt2 = (const float*)d_in[19];
  const float* wt3 = (const float*)d_in[20];
  const float* bt3 = (const float*)d_in[21];
  const float* wt31 = (const float*)d_in[22];
  const float* bt31 = (const float*)d_in[23];
  const float* wt4 = (const float*)d_in[24];
  const float* bt4 = (const float*)d_in[25];

  float* ws = (float*)d_ws;
  float* a1 = ws;               // NHWC [256,32,32,32]  (reused as g3)
  float* a2 = a1 + 8388608;     // NHWC [256,16,16,64]  (reused as g2)
  float* a3 = a2 + 4194304;     // NHWC [256,8,8,128]   (reused as g1)
  float* a4 = a3 + 2097152;     // NHWC [256,4,4,256]   (reused as g0)
  float* g31 = a4 + 1048576;    // NHWC [256,64,64,32]  33554432
  float* d2 = g31;              // [256,8192]
  float* P = g31 + 2097152;     // 262144
  float* csq = g31 + 2359296;   // 8192
  float* a4n = g31 + 2367488;   // NCHW a4 copy
  float* wfcT = g31 + 3416064;  // 1048576
  float* bfcT = g31 + 4464640;  // 4096
  ushort* wTc2 = (ushort*)(g31 + 4468736);  // 18432 bf16
  ushort* wTc3 = (ushort*)(g31 + 4487168);  // 73728 bf16
  ushort* wTc4 = (ushort*)(g31 + 4560896);  // 294912 bf16
  float* ze = g31 + 33554432;   // [256,256]
  float* zq = ze + 65536;
  float* stats = zq + 65536;    // 8 layers x 512
  float* lossacc = stats + 4096;
  int* idx = (int*)(lossacc + 4);
  ushort* wTt1 = (ushort*)(lossacc + 4 + 256);  // 294912 bf16 (parity)
  ushort* wTt2 = wTt1 + 294912;                 // 73728 bf16 (parity)
  ushort* wTt3 = wTt2 + 73728;                  // 18432 bf16 (tap-major)
  ushort* wTt31 = wTt3 + 18432;                 // 9216 bf16 (tap-major)
  float* g3 = a1;
  float* g2 = a2;
  float* g1 = a3;
  float* g0 = a4;

  float* st0 = stats + 0 * 512;
  float* st1 = stats + 1 * 512;
  float* st2 = stats + 2 * 512;
  float* st3 = stats + 3 * 512;
  float* st4 = stats + 4 * 512;
  float* st5 = stats + 5 * 512;
  float* st6 = stats + 6 * 512;
  float* st7 = stats + 7 * 512;

  hipMemsetAsync(stats, 0, (4096 + 8) * sizeof(float), stream);

  // ---- weight transposes (bf16) ----
  tr_convw_bf<<<72, 256, 0, stream>>>(ew2, wTc2, 32, 64, 18432);
  tr_convw_bf<<<288, 256, 0, stream>>>(ew3, wTc3, 64, 128, 73728);
  tr_convw_bf<<<1152, 256, 0, stream>>>(ew4, wTc4, 128, 256, 294912);
  tr_convtw_bf<<<1152, 256, 0, stream>>>(wt1, wTt1, 256, 128, 294912);
  tr_convtw_bf<<<288, 256, 0, stream>>>(wt2, wTt2, 128, 64, 73728);
  tr_convtw_tc<<<72, 256, 0, stream>>>(wt3, wTt3, 64, 32, 18432);
  tr_convtw_tc<<<36, 256, 0, stream>>>(wt31, wTt31, 32, 32, 9216);
  tr_fcdec<<<4096, 256, 0, stream>>>(wfc, bfc, wfcT, bfcT);
  rowsq<<<2048, 256, 0, stream>>>(cb, csq);

  // ---- encoder ----
  conv1<<<dim3(256, 8), 256, 0, stream>>>(x, ew1, eb1, a1, st0);
  mfmaconv<64, 0, 32, 32, 64, true><<<dim3(1, 1024), 256, 0, stream>>>(
      a1, wTc2, eb2, st0, 1.f / (256.f * 1024.f), a2, st1);
  mfmaconv<64, 0, 16, 64, 128, true><<<dim3(2, 256), 256, 0, stream>>>(
      a2, wTc3, eb3, st1, 1.f / (256.f * 256.f), a3, st2);
  mfmaconv<64, 0, 8, 128, 256, true><<<dim3(4, 64), 256, 0, stream>>>(
      a3, wTc4, eb4, st2, 1.f / (256.f * 64.f), a4, st3);
  tr_a4<<<4096, 256, 0, stream>>>(a4, a4n);

  // ---- encoder FC (fp32) ----
  gemm_abt<<<dim3(2, 4, 8), 256, 0, stream>>>(a4n, wmu, nullptr, st3,
                                              1.f / 4096.f, nullptr, P, 4096,
                                              0, 0, 1.f, 0);
  gemm_reduce<<<128, 256, 0, stream>>>(P, ze, bmu, 256, 128, 256, 0, 1.f, 0, 8);
  gemm_abt<<<dim3(2, 4, 8), 256, 0, stream>>>(a4n, wcov, nullptr, st3,
                                              1.f / 4096.f, nullptr, P, 4096,
                                              0, 0, 1.f, 0);
  gemm_reduce<<<128, 256, 0, stream>>>(P, ze, bcov, 256, 128, 256, 128, 1.f, 1, 8);

  // ---- VQ (fp32) ----
  gemm_abt<<<dim3(128, 4, 1), 256, 0, stream>>>(ze, cb, csq, nullptr, 0.f, d2,
                                                nullptr, 256, 8192, 0, -2.f, 0);
  argmin_d2<<<256, 256, 0, stream>>>(d2, idx);
  vq_gather_loss<<<256, 256, 0, stream>>>(ze, cb, idx, zq, lossacc);

  // ---- decoder FC (fp32) ----
  gemm_abt<<<dim3(64, 4, 1), 256, 0, stream>>>(zq, wfcT, bfcT, nullptr, 0.f,
                                               g0, nullptr, 256, 4096, 0, 1.f, 0);

  // ---- decoder ----
  mfmaconv<64, 1, 4, 256, 128, false><<<dim3(2, 64, 4), 256, 0, stream>>>(
      g0, wTt1, bt1, nullptr, 0.f, g1, st4);
  mfmaconv<64, 1, 8, 128, 64, true><<<dim3(1, 256, 4), 256, 0, stream>>>(
      g1, wTt2, bt2, st4, 1.f / (256.f * 64.f), g2, st5);
  convt_mfma<16, 64, true><<<1024, 256, 0, stream>>>(
      g2, wTt3, bt3, st5, 1.f / (256.f * 256.f), g3, st6);
  convt_mfma<32, 32, true><<<4096, 256, 0, stream>>>(
      g3, wTt31, bt31, st6, 1.f / (256.f * 1024.f), g31, st7);

  convt4_tanh<<<4096, 256, 0, stream>>>(g31, wt4, bt4, st7,
                                        1.f / (256.f * 4096.f), (float*)d_out);
  write_loss<<<1, 1, 0, stream>>>(lossacc, (float*)d_out + 3145728);
}